// Round 16
// baseline (703.192 us; speedup 1.0000x reference)
//
#include <hip/hip_runtime.h>
#include <math.h>

#define INC 128
#define HID 64
#define OUTC 40
#define SHIFT 9
#define MAXB 256
#define NPB 64
#define ONB 96
#define LSW 41
#define SRCM 0x1FFFF
#define PLDS 12288

typedef _Float16 half2_t __attribute__((ext_vector_type(2)));

__device__ inline void fma4(float4& a, float s, const float4& w) {
    a.x += s * w.x; a.y += s * w.y; a.z += s * w.z; a.w += s * w.w;
}
__device__ inline unsigned pkh(float a, float b) {
    unsigned short ua = __builtin_bit_cast(unsigned short, (_Float16)a);
    unsigned short ub = __builtin_bit_cast(unsigned short, (_Float16)b);
    return (unsigned)ua | ((unsigned)ub << 16);
}
__device__ inline float fdot2_(unsigned a, unsigned b, float c) {
#if __has_builtin(__builtin_amdgcn_fdot2)
    return __builtin_amdgcn_fdot2(__builtin_bit_cast(half2_t, a),
                                  __builtin_bit_cast(half2_t, b), c, false);
#else
    half2_t ha = __builtin_bit_cast(half2_t, a);
    half2_t hb = __builtin_bit_cast(half2_t, b);
    return fmaf((float)ha[0], (float)hb[0], fmaf((float)ha[1], (float)hb[1], c));
#endif
}
__device__ inline float dot4(const uint4& a, const uint4& b) {
    float d = fdot2_(a.x, b.x, 0.f);
    d = fdot2_(a.y, b.y, d);
    d = fdot2_(a.z, b.z, d);
    d = fdot2_(a.w, b.w, d);
    return d;
}
__device__ inline void unpack8(float* f, const uint4& a) {
    half2_t p;
    p = __builtin_bit_cast(half2_t, a.x); f[0] = (float)p[0]; f[1] = (float)p[1];
    p = __builtin_bit_cast(half2_t, a.y); f[2] = (float)p[0]; f[3] = (float)p[1];
    p = __builtin_bit_cast(half2_t, a.z); f[4] = (float)p[0]; f[5] = (float)p[1];
    p = __builtin_bit_cast(half2_t, a.w); f[6] = (float)p[0]; f[7] = (float)p[1];
}
__device__ inline void dacc4(float4& a, unsigned xp_, const uint4& w) {
    a.x = fdot2_(xp_, w.x, a.x);
    a.y = fdot2_(xp_, w.y, a.y);
    a.z = fdot2_(xp_, w.z, a.z);
    a.w = fdot2_(xp_, w.w, a.w);
}
// packed fp16 accumulate: acc[0..3] += s * a (8 channels, 4 pk_fma)
__device__ inline void pacc(half2_t* acc, float s, const uint4& a) {
    _Float16 hs = (_Float16)s;
    half2_t s2 = {hs, hs};
    acc[0] += s2 * __builtin_bit_cast(half2_t, a.x);
    acc[1] += s2 * __builtin_bit_cast(half2_t, a.y);
    acc[2] += s2 * __builtin_bit_cast(half2_t, a.z);
    acc[3] += s2 * __builtin_bit_cast(half2_t, a.w);
}
template<int CTRL>
__device__ inline float dppadd(float d) {
    int x = __builtin_amdgcn_update_dpp(0, __builtin_bit_cast(int, d),
                                        CTRL, 0xf, 0xf, true);
    return d + __builtin_bit_cast(float, x);
}
__device__ inline float red8(float d) {
    d = dppadd<0xB1>(d);    // quad_perm xor1
    d = dppadd<0x4E>(d);    // quad_perm xor2
    d = dppadd<0x141>(d);   // row_half_mirror
    return d;
}
__device__ inline float red16(float d) {
    d = dppadd<0xB1>(d);
    d = dppadd<0x4E>(d);
    d = dppadd<0x141>(d);
    d = dppadd<0x140>(d);
    return d;
}
#define EXP2(x) __builtin_amdgcn_exp2f(x)

// ---------------- CSR build: bucketed counting sort (no self loops) ----------------

__global__ __launch_bounds__(256) void k_hist(const int* __restrict__ ei, int E,
                                              int* __restrict__ bucket_cnt,
                                              int* __restrict__ blk_cnt, int nbuck) {
    __shared__ int lh[MAXB];
    int tid = threadIdx.x;
    for (int i = tid; i < nbuck; i += 256) lh[i] = 0;
    __syncthreads();
    int base = blockIdx.x * 4096;
    int end = min(base + 4096, E);
    for (int e = base + tid; e < end; e += 256)
        atomicAdd(&lh[ei[E + e] >> SHIFT], 1);
    __syncthreads();
    for (int i = tid; i < nbuck; i += 256) {
        int v = lh[i];
        blk_cnt[blockIdx.x * MAXB + i] = v;
        if (v) atomicAdd(&bucket_cnt[i], v);
    }
}

__global__ __launch_bounds__(256) void k_bscan(const int* __restrict__ bucket_cnt,
                                               int* __restrict__ pair_base,
                                               int* __restrict__ pair_fill,
                                               int* __restrict__ row_ptr,
                                               int* __restrict__ csr_src,
                                               int n, int E, int nbuck) {
    __shared__ int tmp[MAXB];
    int tid = threadIdx.x;
    int cnt = (tid < nbuck) ? bucket_cnt[tid] : 0;
    tmp[tid] = cnt;
    __syncthreads();
    for (int off = 1; off < 256; off <<= 1) {
        int t = (tid >= off) ? tmp[tid - off] : 0;
        __syncthreads();
        tmp[tid] += t;
        __syncthreads();
    }
    if (tid < nbuck) { int pb = tmp[tid] - cnt; pair_base[tid] = pb; pair_fill[tid] = pb; }
    if (tid == 0) row_ptr[n] = E;
    if (tid < 16) csr_src[E + tid] = 0;   // pad: clamp-free pipelined reads
}

__global__ __launch_bounds__(256) void k_bin(const int* __restrict__ ei, int E,
                                             const int* __restrict__ blk_cnt,
                                             int* __restrict__ pair_fill,
                                             unsigned* __restrict__ pairs, int nbuck) {
    __shared__ int lbase[MAXB];
    int tid = threadIdx.x;
    for (int i = tid; i < nbuck; i += 256) {
        int v = blk_cnt[blockIdx.x * MAXB + i];
        lbase[i] = v ? atomicAdd(&pair_fill[i], v) : 0;
    }
    __syncthreads();
    int base = blockIdx.x * 4096;
    int end = min(base + 4096, E);
    for (int e = base + tid; e < end; e += 256) {
        int s = ei[e], d = ei[E + e];
        int pos = atomicAdd(&lbase[d >> SHIFT], 1);
        pairs[pos] = (unsigned)s | ((unsigned)(d & ((1 << SHIFT) - 1)) << 17);
    }
}

__global__ __launch_bounds__(256) void k_build(const unsigned* __restrict__ pairs,
                                               const int* __restrict__ pair_base,
                                               const int* __restrict__ bucket_cnt,
                                               int* __restrict__ row_ptr,
                                               int* __restrict__ csr_src,
                                               int* __restrict__ dhist, int n) {
    __shared__ int cnt[1 << SHIFT];
    __shared__ int offs[1 << SHIFT];
    __shared__ int stmp[256];
    __shared__ unsigned plds[PLDS];
    int b = blockIdx.x;
    int tid = threadIdx.x;
    int nb0 = b << SHIFT;
    int W = min(n - nb0, 1 << SHIFT);
    int p0 = pair_base[b], pc = bucket_cnt[b];
    bool inl = (pc <= PLDS);

    cnt[tid] = 0; cnt[tid + 256] = 0;
    if (inl) for (int i = tid; i < pc; i += 256) plds[i] = pairs[p0 + i];
    __syncthreads();
    if (inl) {
        for (int i = tid; i < pc; i += 256) atomicAdd(&cnt[plds[i] >> 17], 1);
    } else {
        for (int i = tid; i < pc; i += 256) atomicAdd(&cnt[pairs[p0 + i] >> 17], 1);
    }
    __syncthreads();

    int i0 = 2 * tid, i1 = 2 * tid + 1;
    int s0 = (i0 < W) ? cnt[i0] : 0;
    int s1 = (i1 < W) ? cnt[i1] : 0;
    // degree histogram for the degree-sorted schedule
    if (i0 < W) atomicAdd(&dhist[min(s0, 255)], 1);
    if (i1 < W) atomicAdd(&dhist[min(s1, 255)], 1);
    int ps = s0 + s1;
    stmp[tid] = ps;
    __syncthreads();
    for (int off = 1; off < 256; off <<= 1) {
        int t = (tid >= off) ? stmp[tid - off] : 0;
        __syncthreads();
        stmp[tid] += t;
        __syncthreads();
    }
    int excl = stmp[tid] - ps;
    if (i0 < W) { row_ptr[nb0 + i0] = p0 + excl;      offs[i0] = excl; }
    if (i1 < W) { row_ptr[nb0 + i1] = p0 + excl + s0; offs[i1] = excl + s0; }
    __syncthreads();
    if (inl) {
        for (int i = tid; i < pc; i += 256) {
            unsigned pr = plds[i];
            int pos = atomicAdd(&offs[pr >> 17], 1);
            csr_src[p0 + pos] = (int)(pr & SRCM);
        }
    } else {
        for (int i = tid; i < pc; i += 256) {
            unsigned pr = pairs[p0 + i];
            int pos = atomicAdd(&offs[pr >> 17], 1);
            csr_src[p0 + pos] = (int)(pr & SRCM);
        }
    }
}

// degree counting-sort: scan 256 bins (1 block), then scatter node ids
__global__ void k_dscan(int* __restrict__ dhist) {
    __shared__ int tmp[256];
    int tid = threadIdx.x;
    int v = dhist[tid];
    tmp[tid] = v;
    __syncthreads();
    for (int off = 1; off < 256; off <<= 1) {
        int t = (tid >= off) ? tmp[tid - off] : 0;
        __syncthreads();
        tmp[tid] += t;
        __syncthreads();
    }
    dhist[tid] = tmp[tid] - v;     // exclusive base; reused as fill
}

__global__ __launch_bounds__(256) void k_dscatter(const int* __restrict__ row_ptr,
                                                  int* __restrict__ dfill,
                                                  int* __restrict__ order, int n) {
    int v = blockIdx.x * 256 + threadIdx.x;
    if (v < n) {
        int deg = min(row_ptr[v + 1] - row_ptr[v], 255);
        int pos = atomicAdd(&dfill[deg], 1);
        order[pos] = v;
    }
}

// ---------------- Linear1: fp16-pair dot2 GEMM + ReLU + normalize, fp16 out ----------------

__global__ __launch_bounds__(256, 4) void k_linear1(const float* __restrict__ x,
                                                    const float* __restrict__ W1,
                                                    const float* __restrict__ b1,
                                                    uint2* __restrict__ X1,
                                                    float* __restrict__ nrm1, int n) {
    __shared__ unsigned Wp[64 * 64];
    __shared__ unsigned xp[64 * 64];
    int tid = threadIdx.x;
    int base = blockIdx.x * NPB;

    for (int t = tid; t < 1024; t += 256) {
        int kp = t >> 4;
        int c4 = t & 15;
        float4 a = ((const float4*)W1)[(2 * kp) * 16 + c4];
        float4 b = ((const float4*)W1)[(2 * kp + 1) * 16 + c4];
        uint4 w;
        w.x = pkh(a.x, b.x); w.y = pkh(a.y, b.y);
        w.z = pkh(a.z, b.z); w.w = pkh(a.w, b.w);
        *(uint4*)&Wp[kp * 64 + c4 * 4] = w;
    }
    for (int t = tid; t < 1024; t += 256) {
        int nl = t >> 4;
        int k8 = t & 15;
        int gn = base + nl;
        float4 a, b;
        if (gn < n) {
            a = ((const float4*)x)[(size_t)gn * 32 + k8 * 2];
            b = ((const float4*)x)[(size_t)gn * 32 + k8 * 2 + 1];
        } else { a = make_float4(0,0,0,0); b = a; }
        uint4 v;
        v.x = pkh(a.x, a.y); v.y = pkh(a.z, a.w);
        v.z = pkh(b.x, b.y); v.w = pkh(b.z, b.w);
        int key = ((nl >> 2) & 3) << 2;
        *(uint4*)&xp[nl * 64 + ((k8 * 4) ^ key)] = v;
    }
    __syncthreads();

    int cg = tid & 15;
    int ng = tid >> 4;
    int n0 = ng * 4;
    const int key = (ng & 3) << 2;
    float4 acc0 = {0,0,0,0}, acc1 = {0,0,0,0}, acc2 = {0,0,0,0}, acc3 = {0,0,0,0};

    #pragma unroll 4
    for (int k4 = 0; k4 < 64; k4 += 4) {
        uint4 xq0 = *(uint4*)&xp[(n0 + 0) * 64 + (k4 ^ key)];
        uint4 xq1 = *(uint4*)&xp[(n0 + 1) * 64 + (k4 ^ key)];
        uint4 xq2 = *(uint4*)&xp[(n0 + 2) * 64 + (k4 ^ key)];
        uint4 xq3 = *(uint4*)&xp[(n0 + 3) * 64 + (k4 ^ key)];
        uint4 wq0 = *(uint4*)&Wp[(k4 + 0) * 64 + cg * 4];
        uint4 wq1 = *(uint4*)&Wp[(k4 + 1) * 64 + cg * 4];
        uint4 wq2 = *(uint4*)&Wp[(k4 + 2) * 64 + cg * 4];
        uint4 wq3 = *(uint4*)&Wp[(k4 + 3) * 64 + cg * 4];
        dacc4(acc0, xq0.x, wq0); dacc4(acc0, xq0.y, wq1); dacc4(acc0, xq0.z, wq2); dacc4(acc0, xq0.w, wq3);
        dacc4(acc1, xq1.x, wq0); dacc4(acc1, xq1.y, wq1); dacc4(acc1, xq1.z, wq2); dacc4(acc1, xq1.w, wq3);
        dacc4(acc2, xq2.x, wq0); dacc4(acc2, xq2.y, wq1); dacc4(acc2, xq2.z, wq2); dacc4(acc2, xq2.w, wq3);
        dacc4(acc3, xq3.x, wq0); dacc4(acc3, xq3.y, wq1); dacc4(acc3, xq3.z, wq2); dacc4(acc3, xq3.w, wq3);
    }

    float4 bb = ((const float4*)b1)[cg];
    float4 r[4] = {acc0, acc1, acc2, acc3};
    #pragma unroll
    for (int nl = 0; nl < 4; ++nl) {
        int node = base + n0 + nl;
        float4 v = r[nl];
        v.x = fmaxf(v.x + bb.x, 0.f); v.y = fmaxf(v.y + bb.y, 0.f);
        v.z = fmaxf(v.z + bb.z, 0.f); v.w = fmaxf(v.w + bb.w, 0.f);
        float q = v.x * v.x + v.y * v.y + v.z * v.z + v.w * v.w;
        q = red16(q);
        float rq = rsqrtf(fmaxf(q, 1e-24f));
        if (node < n) {
            X1[(size_t)node * 16 + cg] = make_uint2(pkh(v.x * rq, v.y * rq),
                                                    pkh(v.z * rq, v.w * rq));
            if (cg == 0) nrm1[node] = sqrtf(fmaxf(q, 1e-24f));
        }
    }
}

// ---------------- AGNN propagation ----------------
// one 8-lane group per node (degree-sorted schedule); 2-edge pipelined chains;
// packed fp16 accumulation; no cross-group reduce

template<bool HFOUT>
__global__ __launch_bounds__(256) void k_prop(const uint4* __restrict__ X,
                                              const float* __restrict__ nrm,
                                              const int* __restrict__ row_ptr,
                                              const int* __restrict__ csr_src,
                                              const int* __restrict__ order,
                                              const float* __restrict__ beta_ptr,
                                              uint4* __restrict__ Xout,
                                              float* __restrict__ nrm_out, int n) {
    int gid = (blockIdx.x << 5) + (threadIdx.x >> 3);
    if (gid >= n) return;
    int node = order[gid];
    int gl = threadIdx.x & 7;
    float beta = beta_ptr ? beta_ptr[0] : 1.0f;
    float b2 = beta * 1.4426950408889634f;

    uint4 hdp = X[(unsigned)node * 8u + gl];
    int s0 = row_ptr[node], s1 = row_ptr[node + 1];
    float nd = nrm[node];

    // self-edge: dot(xn,xn)=1 by construction (zero rows: weight exp(0)=1)
    float eself = (nd > 1.5e-12f) ? EXP2(b2) : 1.0f;
    float den = eself;
    half2_t acc[4] = {{0,0},{0,0},{0,0},{0,0}};
    pacc(acc, eself * nd, hdp);

    if (s0 < s1) {
        int i0 = csr_src[s0];
        int i1 = csr_src[s0 + 1];            // padded / in-bounds; gated by v1
        uint4 a0 = X[(unsigned)i0 * 8u + gl];
        uint4 a1 = X[(unsigned)i1 * 8u + gl];
        float n0 = nrm[i0], n1 = nrm[i1];
        bool v1 = s0 + 1 < s1;
        for (int j = s0 + 2; j < s1; j += 2) {
            int i0n = csr_src[j];
            int i1n = csr_src[j + 1];
            uint4 a0n = X[(unsigned)i0n * 8u + gl];
            uint4 a1n = X[(unsigned)i1n * 8u + gl];
            float n0n = nrm[i0n], n1n = nrm[i1n];
            float d0 = red8(dot4(a0, hdp));
            float d1 = red8(dot4(a1, hdp));
            float e0 = EXP2(b2 * d0);
            float e1 = v1 ? EXP2(b2 * d1) : 0.f;
            den += e0 + e1;
            pacc(acc, e0 * n0, a0);
            pacc(acc, e1 * n1, a1);
            a0 = a0n; a1 = a1n; n0 = n0n; n1 = n1n;
            v1 = j + 1 < s1;
        }
        float d0 = red8(dot4(a0, hdp));
        float d1 = red8(dot4(a1, hdp));
        float e0 = EXP2(b2 * d0);
        float e1 = v1 ? EXP2(b2 * d1) : 0.f;
        den += e0 + e1;
        pacc(acc, e0 * n0, a0);
        pacc(acc, e1 * n1, a1);
    }

    float inv = 1.0f / den;
    float o[8];
    #pragma unroll
    for (int c = 0; c < 4; ++c) {
        o[2 * c]     = (float)acc[c][0] * inv;
        o[2 * c + 1] = (float)acc[c][1] * inv;
    }

    if (HFOUT) {
        float q = 0.f;
        #pragma unroll
        for (int c = 0; c < 8; ++c) q += o[c] * o[c];
        q = red8(q);
        float rq = rsqrtf(fmaxf(q, 1e-24f));
        uint4 w;
        w.x = pkh(o[0] * rq, o[1] * rq);
        w.y = pkh(o[2] * rq, o[3] * rq);
        w.z = pkh(o[4] * rq, o[5] * rq);
        w.w = pkh(o[6] * rq, o[7] * rq);
        Xout[(unsigned)node * 8u + gl] = w;
        if (gl == 0) nrm_out[node] = sqrtf(fmaxf(q, 1e-24f));
    } else {
        uint4 w;
        w.x = pkh(o[0], o[1]); w.y = pkh(o[2], o[3]);
        w.z = pkh(o[4], o[5]); w.w = pkh(o[6], o[7]);
        Xout[(unsigned)node * 8u + gl] = w;
    }
}

// ---------------- Linear2 + log_softmax: register-tiled, fp16 input ----------------

__global__ __launch_bounds__(256) void k_out(const uint4* __restrict__ Xh,
                                             const float* __restrict__ W2,
                                             const float* __restrict__ b2,
                                             float* __restrict__ out, int n) {
    __shared__ float hs[ONB * HID];
    __shared__ float W2s[HID * OUTC];
    __shared__ float ls[ONB * LSW];
    int tid = threadIdx.x;
    int base = blockIdx.x * ONB;

    for (int i = tid; i < HID * OUTC / 4; i += 256)
        ((float4*)W2s)[i] = ((const float4*)W2)[i];
    for (int i = tid; i < ONB * 8; i += 256) {
        int nl = i >> 3, k8 = i & 7;
        int gn = base + nl;
        uint4 v = (gn < n) ? Xh[(size_t)gn * 8 + k8] : make_uint4(0, 0, 0, 0);
        float f[8]; unpack8(f, v);
        int key = ((nl >> 2) & 7) << 2;
        *(float4*)&hs[nl * HID + ((k8 * 8) ^ key)]     = make_float4(f[0], f[1], f[2], f[3]);
        *(float4*)&hs[nl * HID + ((k8 * 8 + 4) ^ key)] = make_float4(f[4], f[5], f[6], f[7]);
    }
    __syncthreads();

    if (tid < 240) {
        int ng = tid / 10, cg = tid % 10;
        int n0 = ng * 4;
        const int sw = ((ng & 7) << 2);
        float4 acc0 = {0,0,0,0}, acc1 = {0,0,0,0}, acc2 = {0,0,0,0}, acc3 = {0,0,0,0};
        #pragma unroll 4
        for (int k = 0; k < HID; k += 4) {
            float4 w0 = *(float4*)&W2s[(k + 0) * OUTC + cg * 4];
            float4 w1 = *(float4*)&W2s[(k + 1) * OUTC + cg * 4];
            float4 w2 = *(float4*)&W2s[(k + 2) * OUTC + cg * 4];
            float4 w3 = *(float4*)&W2s[(k + 3) * OUTC + cg * 4];
            float4 x0 = *(float4*)&hs[(n0 + 0) * HID + (k ^ sw)];
            float4 x1 = *(float4*)&hs[(n0 + 1) * HID + (k ^ sw)];
            float4 x2 = *(float4*)&hs[(n0 + 2) * HID + (k ^ sw)];
            float4 x3 = *(float4*)&hs[(n0 + 3) * HID + (k ^ sw)];
            fma4(acc0, x0.x, w0); fma4(acc0, x0.y, w1); fma4(acc0, x0.z, w2); fma4(acc0, x0.w, w3);
            fma4(acc1, x1.x, w0); fma4(acc1, x1.y, w1); fma4(acc1, x1.z, w2); fma4(acc1, x1.w, w3);
            fma4(acc2, x2.x, w0); fma4(acc2, x2.y, w1); fma4(acc2, x2.z, w2); fma4(acc2, x2.w, w3);
            fma4(acc3, x3.x, w0); fma4(acc3, x3.y, w1); fma4(acc3, x3.z, w2); fma4(acc3, x3.w, w3);
        }
        float4 bb = ((const float4*)b2)[cg];
        float4 rr[4] = {acc0, acc1, acc2, acc3};
        #pragma unroll
        for (int i = 0; i < 4; ++i) {
            int lb = (n0 + i) * LSW + cg * 4;
            ls[lb + 0] = rr[i].x + bb.x;
            ls[lb + 1] = rr[i].y + bb.y;
            ls[lb + 2] = rr[i].z + bb.z;
            ls[lb + 3] = rr[i].w + bb.w;
        }
    }
    __syncthreads();

    if (tid < ONB) {
        int node = base + tid;
        if (node < n) {
            float m = -INFINITY;
            #pragma unroll
            for (int c = 0; c < OUTC; ++c) m = fmaxf(m, ls[tid * LSW + c]);
            float z = 0.f;
            #pragma unroll
            for (int c = 0; c < OUTC; ++c) z += __expf(ls[tid * LSW + c] - m);
            float lz = m + __logf(z);
            #pragma unroll
            for (int c = 0; c < OUTC; ++c)
                out[(size_t)node * OUTC + c] = ls[tid * LSW + c] - lz;
        }
    }
}

// ---------------- launch ----------------

extern "C" void kernel_launch(void* const* d_in, const int* in_sizes, int n_in,
                              void* d_out, int out_size, void* d_ws, size_t ws_size,
                              hipStream_t stream) {
    const float* x   = (const float*)d_in[0];
    const int*   ei  = (const int*)d_in[1];
    const float* W1  = (const float*)d_in[2];
    const float* b1  = (const float*)d_in[3];
    const float* W2  = (const float*)d_in[4];
    const float* b2  = (const float*)d_in[5];
    const float* beta2 = (const float*)d_in[6];
    float* out = (float*)d_out;

    const int n = in_sizes[0] / INC;       // 100000
    const int E = in_sizes[1] / 2;         // 1600000
    const int nbuck = (n + (1 << SHIFT) - 1) >> SHIFT;   // 196
    const int cgrid = (E + 4095) / 4096;   // 391

    // workspace layout
    char* p = (char*)d_ws;
    uint4* X1 = (uint4*)p;             p += (size_t)n * 8 * 16;
    uint4* X2 = (uint4*)p;             p += (size_t)n * 8 * 16;
    uint4* X3 = (uint4*)p;             p += (size_t)n * 8 * 16;
    float* nrm1 = (float*)p;           p += (size_t)n * 4;
    float* nrm2 = (float*)p;           p += (size_t)n * 4;
    int* order = (int*)p;              p += (size_t)n * 4;
    int* bucket_cnt  = (int*)p;        p += MAXB * 4;
    int* dhist       = (int*)p;        p += 256 * 4;      // contiguous with bucket_cnt
    int* pair_base   = (int*)p;        p += MAXB * 4;
    int* pair_fill   = (int*)p;        p += MAXB * 4;
    int* row_ptr = (int*)p;            p += (size_t)(n + 1) * 4;
    int* csr_src = (int*)p;            p += (size_t)(E + 16) * 4;
    int* blk_cnt = (int*)p;            p += (size_t)cgrid * MAXB * 4;
    unsigned* pairs = (unsigned*)X3;   // alias: pairs dead before prop2 writes X3

    // CSR build + degree sort
    (void)hipMemsetAsync(bucket_cnt, 0, (MAXB + 256) * 4, stream);
    k_hist<<<cgrid, 256, 0, stream>>>(ei, E, bucket_cnt, blk_cnt, nbuck);
    k_bscan<<<1, 256, 0, stream>>>(bucket_cnt, pair_base, pair_fill, row_ptr, csr_src,
                                   n, E, nbuck);
    k_bin<<<cgrid, 256, 0, stream>>>(ei, E, blk_cnt, pair_fill, pairs, nbuck);
    k_build<<<nbuck, 256, 0, stream>>>(pairs, pair_base, bucket_cnt, row_ptr, csr_src,
                                       dhist, n);
    k_dscan<<<1, 256, 0, stream>>>(dhist);
    k_dscatter<<<(n + 255) / 256, 256, 0, stream>>>(row_ptr, dhist, order, n);

    // MLP front + props + head
    k_linear1<<<(n + NPB - 1) / NPB, 256, 0, stream>>>(x, W1, b1, (uint2*)X1, nrm1, n);
    int pgrid = (n + 31) / 32;
    k_prop<true><<<pgrid, 256, 0, stream>>>(X1, nrm1, row_ptr, csr_src, order, nullptr,
                                            X2, nrm2, n);
    k_prop<false><<<pgrid, 256, 0, stream>>>(X2, nrm2, row_ptr, csr_src, order, beta2,
                                             X3, nullptr, n);
    k_out<<<(n + ONB - 1) / ONB, 256, 0, stream>>>(X3, W2, b2, out, n);
}

// Round 17
// 195.322 us; speedup vs baseline: 3.6002x; 3.6002x over previous
//
#include <hip/hip_runtime.h>
#include <math.h>

#define INC 128
#define HID 64
#define OUTC 40
#define SHIFT 9
#define MAXB 256
#define NPB 64
#define ONB 96
#define LSW 41
#define SRCM 0x1FFFF
#define PLDS 12288

typedef _Float16 half2_t __attribute__((ext_vector_type(2)));

__device__ inline void fma4(float4& a, float s, const float4& w) {
    a.x += s * w.x; a.y += s * w.y; a.z += s * w.z; a.w += s * w.w;
}
__device__ inline unsigned pkh(float a, float b) {
    unsigned short ua = __builtin_bit_cast(unsigned short, (_Float16)a);
    unsigned short ub = __builtin_bit_cast(unsigned short, (_Float16)b);
    return (unsigned)ua | ((unsigned)ub << 16);
}
__device__ inline float fdot2_(unsigned a, unsigned b, float c) {
#if __has_builtin(__builtin_amdgcn_fdot2)
    return __builtin_amdgcn_fdot2(__builtin_bit_cast(half2_t, a),
                                  __builtin_bit_cast(half2_t, b), c, false);
#else
    half2_t ha = __builtin_bit_cast(half2_t, a);
    half2_t hb = __builtin_bit_cast(half2_t, b);
    return fmaf((float)ha[0], (float)hb[0], fmaf((float)ha[1], (float)hb[1], c));
#endif
}
__device__ inline float dot4(const uint4& a, const uint4& b) {
    float d = fdot2_(a.x, b.x, 0.f);
    d = fdot2_(a.y, b.y, d);
    d = fdot2_(a.z, b.z, d);
    d = fdot2_(a.w, b.w, d);
    return d;
}
__device__ inline void unpack8(float* f, const uint4& a) {
    half2_t p;
    p = __builtin_bit_cast(half2_t, a.x); f[0] = (float)p[0]; f[1] = (float)p[1];
    p = __builtin_bit_cast(half2_t, a.y); f[2] = (float)p[0]; f[3] = (float)p[1];
    p = __builtin_bit_cast(half2_t, a.z); f[4] = (float)p[0]; f[5] = (float)p[1];
    p = __builtin_bit_cast(half2_t, a.w); f[6] = (float)p[0]; f[7] = (float)p[1];
}
__device__ inline void dacc4(float4& a, unsigned xp_, const uint4& w) {
    a.x = fdot2_(xp_, w.x, a.x);
    a.y = fdot2_(xp_, w.y, a.y);
    a.z = fdot2_(xp_, w.z, a.z);
    a.w = fdot2_(xp_, w.w, a.w);
}
// packed fp16 accumulate: acc[0..3] += s * a (8 channels, 4 pk_fma)
__device__ inline void pacc(half2_t* acc, float s, const uint4& a) {
    _Float16 hs = (_Float16)s;
    half2_t s2 = {hs, hs};
    acc[0] += s2 * __builtin_bit_cast(half2_t, a.x);
    acc[1] += s2 * __builtin_bit_cast(half2_t, a.y);
    acc[2] += s2 * __builtin_bit_cast(half2_t, a.z);
    acc[3] += s2 * __builtin_bit_cast(half2_t, a.w);
}
template<int CTRL>
__device__ inline float dppadd(float d) {
    int x = __builtin_amdgcn_update_dpp(0, __builtin_bit_cast(int, d),
                                        CTRL, 0xf, 0xf, true);
    return d + __builtin_bit_cast(float, x);
}
__device__ inline float red8(float d) {
    d = dppadd<0xB1>(d);    // quad_perm xor1
    d = dppadd<0x4E>(d);    // quad_perm xor2
    d = dppadd<0x141>(d);   // row_half_mirror
    return d;
}
__device__ inline float red16(float d) {
    d = dppadd<0xB1>(d);
    d = dppadd<0x4E>(d);
    d = dppadd<0x141>(d);
    d = dppadd<0x140>(d);
    return d;
}
#define EXP2(x) __builtin_amdgcn_exp2f(x)

// ---------------- CSR build: bucketed counting sort (no self loops) ----------------

__global__ __launch_bounds__(256) void k_hist(const int* __restrict__ ei, int E,
                                              int* __restrict__ bucket_cnt,
                                              int* __restrict__ blk_cnt, int nbuck) {
    __shared__ int lh[MAXB];
    int tid = threadIdx.x;
    for (int i = tid; i < nbuck; i += 256) lh[i] = 0;
    __syncthreads();
    int base = blockIdx.x * 4096;
    int end = min(base + 4096, E);
    for (int e = base + tid; e < end; e += 256)
        atomicAdd(&lh[ei[E + e] >> SHIFT], 1);
    __syncthreads();
    for (int i = tid; i < nbuck; i += 256) {
        int v = lh[i];
        blk_cnt[blockIdx.x * MAXB + i] = v;
        if (v) atomicAdd(&bucket_cnt[i], v);
    }
}

__global__ __launch_bounds__(256) void k_bscan(const int* __restrict__ bucket_cnt,
                                               int* __restrict__ pair_base,
                                               int* __restrict__ pair_fill,
                                               int* __restrict__ row_ptr,
                                               int* __restrict__ csr_src,
                                               int n, int E, int nbuck) {
    __shared__ int tmp[MAXB];
    int tid = threadIdx.x;
    int cnt = (tid < nbuck) ? bucket_cnt[tid] : 0;
    tmp[tid] = cnt;
    __syncthreads();
    for (int off = 1; off < 256; off <<= 1) {
        int t = (tid >= off) ? tmp[tid - off] : 0;
        __syncthreads();
        tmp[tid] += t;
        __syncthreads();
    }
    if (tid < nbuck) { int pb = tmp[tid] - cnt; pair_base[tid] = pb; pair_fill[tid] = pb; }
    if (tid == 0) row_ptr[n] = E;
    if (tid < 16) csr_src[E + tid] = 0;   // pad: clamp-free pipelined reads
}

__global__ __launch_bounds__(256) void k_bin(const int* __restrict__ ei, int E,
                                             const int* __restrict__ blk_cnt,
                                             int* __restrict__ pair_fill,
                                             unsigned* __restrict__ pairs, int nbuck) {
    __shared__ int lbase[MAXB];
    int tid = threadIdx.x;
    for (int i = tid; i < nbuck; i += 256) {
        int v = blk_cnt[blockIdx.x * MAXB + i];
        lbase[i] = v ? atomicAdd(&pair_fill[i], v) : 0;
    }
    __syncthreads();
    int base = blockIdx.x * 4096;
    int end = min(base + 4096, E);
    for (int e = base + tid; e < end; e += 256) {
        int s = ei[e], d = ei[E + e];
        int pos = atomicAdd(&lbase[d >> SHIFT], 1);
        pairs[pos] = (unsigned)s | ((unsigned)(d & ((1 << SHIFT) - 1)) << 17);
    }
}

__global__ __launch_bounds__(256) void k_build(const unsigned* __restrict__ pairs,
                                               const int* __restrict__ pair_base,
                                               const int* __restrict__ bucket_cnt,
                                               int* __restrict__ row_ptr,
                                               int* __restrict__ csr_src, int n) {
    __shared__ int cnt[1 << SHIFT];
    __shared__ int offs[1 << SHIFT];
    __shared__ int stmp[256];
    __shared__ unsigned plds[PLDS];
    int b = blockIdx.x;
    int tid = threadIdx.x;
    int nb0 = b << SHIFT;
    int W = min(n - nb0, 1 << SHIFT);
    int p0 = pair_base[b], pc = bucket_cnt[b];
    bool inl = (pc <= PLDS);

    cnt[tid] = 0; cnt[tid + 256] = 0;
    if (inl) for (int i = tid; i < pc; i += 256) plds[i] = pairs[p0 + i];
    __syncthreads();
    if (inl) {
        for (int i = tid; i < pc; i += 256) atomicAdd(&cnt[plds[i] >> 17], 1);
    } else {
        for (int i = tid; i < pc; i += 256) atomicAdd(&cnt[pairs[p0 + i] >> 17], 1);
    }
    __syncthreads();

    int i0 = 2 * tid, i1 = 2 * tid + 1;
    int s0 = (i0 < W) ? cnt[i0] : 0;
    int s1 = (i1 < W) ? cnt[i1] : 0;
    int ps = s0 + s1;
    stmp[tid] = ps;
    __syncthreads();
    for (int off = 1; off < 256; off <<= 1) {
        int t = (tid >= off) ? stmp[tid - off] : 0;
        __syncthreads();
        stmp[tid] += t;
        __syncthreads();
    }
    int excl = stmp[tid] - ps;
    if (i0 < W) { row_ptr[nb0 + i0] = p0 + excl;      offs[i0] = excl; }
    if (i1 < W) { row_ptr[nb0 + i1] = p0 + excl + s0; offs[i1] = excl + s0; }
    __syncthreads();
    if (inl) {
        for (int i = tid; i < pc; i += 256) {
            unsigned pr = plds[i];
            int pos = atomicAdd(&offs[pr >> 17], 1);
            csr_src[p0 + pos] = (int)(pr & SRCM);
        }
    } else {
        for (int i = tid; i < pc; i += 256) {
            unsigned pr = pairs[p0 + i];
            int pos = atomicAdd(&offs[pr >> 17], 1);
            csr_src[p0 + pos] = (int)(pr & SRCM);
        }
    }
}

// ---------------- degree sort (contention-free) ----------------
// per-block LDS histogram of degrees
__global__ __launch_bounds__(256) void k_dhist(const int* __restrict__ row_ptr,
                                               int* __restrict__ blk_dcnt, int n) {
    __shared__ int lh[256];
    int tid = threadIdx.x;
    lh[tid] = 0;
    __syncthreads();
    int v = blockIdx.x * 256 + tid;
    if (v < n) {
        int deg = min(row_ptr[v + 1] - row_ptr[v], 255);
        atomicAdd(&lh[deg], 1);
    }
    __syncthreads();
    blk_dcnt[blockIdx.x * 256 + tid] = lh[tid];
}

// per-bin exclusive prefix over blocks; totals -> dhist. one block per bin.
__global__ __launch_bounds__(512) void k_dcol(int* __restrict__ blk_dcnt,
                                              int* __restrict__ dhist, int nblk) {
    __shared__ int tmp[512];
    int b = blockIdx.x;
    int t = threadIdx.x;
    int v = (t < nblk) ? blk_dcnt[t * 256 + b] : 0;
    tmp[t] = v;
    __syncthreads();
    for (int off = 1; off < 512; off <<= 1) {
        int u = (t >= off) ? tmp[t - off] : 0;
        __syncthreads();
        tmp[t] += u;
        __syncthreads();
    }
    if (t < nblk) blk_dcnt[t * 256 + b] = tmp[t] - v;   // exclusive prefix
    if (t == 511) dhist[b] = tmp[511];                  // bin total
}

// scan bin totals -> global bases (in place)
__global__ void k_dscan(int* __restrict__ dhist) {
    __shared__ int tmp[256];
    int tid = threadIdx.x;
    int v = dhist[tid];
    tmp[tid] = v;
    __syncthreads();
    for (int off = 1; off < 256; off <<= 1) {
        int t = (tid >= off) ? tmp[tid - off] : 0;
        __syncthreads();
        tmp[tid] += t;
        __syncthreads();
    }
    dhist[tid] = tmp[tid] - v;     // exclusive base
}

// scatter: pos = base[deg] + block prefix + LDS-local offset (no global atomics)
__global__ __launch_bounds__(256) void k_dscatter(const int* __restrict__ row_ptr,
                                                  const int* __restrict__ dhist,
                                                  const int* __restrict__ blk_dcnt,
                                                  int* __restrict__ order, int n) {
    __shared__ int lh[256];
    int tid = threadIdx.x;
    lh[tid] = 0;
    __syncthreads();
    int v = blockIdx.x * 256 + tid;
    int deg = 0, loc = 0;
    bool act = v < n;
    if (act) {
        deg = min(row_ptr[v + 1] - row_ptr[v], 255);
        loc = atomicAdd(&lh[deg], 1);
    }
    if (act) {
        int pos = dhist[deg] + blk_dcnt[blockIdx.x * 256 + deg] + loc;
        order[pos] = v;
    }
}

// ---------------- Linear1: fp16-pair dot2 GEMM + ReLU + normalize, fp16 out ----------------

__global__ __launch_bounds__(256, 4) void k_linear1(const float* __restrict__ x,
                                                    const float* __restrict__ W1,
                                                    const float* __restrict__ b1,
                                                    uint2* __restrict__ X1,
                                                    float* __restrict__ nrm1, int n) {
    __shared__ unsigned Wp[64 * 64];
    __shared__ unsigned xp[64 * 64];
    int tid = threadIdx.x;
    int base = blockIdx.x * NPB;

    for (int t = tid; t < 1024; t += 256) {
        int kp = t >> 4;
        int c4 = t & 15;
        float4 a = ((const float4*)W1)[(2 * kp) * 16 + c4];
        float4 b = ((const float4*)W1)[(2 * kp + 1) * 16 + c4];
        uint4 w;
        w.x = pkh(a.x, b.x); w.y = pkh(a.y, b.y);
        w.z = pkh(a.z, b.z); w.w = pkh(a.w, b.w);
        *(uint4*)&Wp[kp * 64 + c4 * 4] = w;
    }
    for (int t = tid; t < 1024; t += 256) {
        int nl = t >> 4;
        int k8 = t & 15;
        int gn = base + nl;
        float4 a, b;
        if (gn < n) {
            a = ((const float4*)x)[(size_t)gn * 32 + k8 * 2];
            b = ((const float4*)x)[(size_t)gn * 32 + k8 * 2 + 1];
        } else { a = make_float4(0,0,0,0); b = a; }
        uint4 v;
        v.x = pkh(a.x, a.y); v.y = pkh(a.z, a.w);
        v.z = pkh(b.x, b.y); v.w = pkh(b.z, b.w);
        int key = ((nl >> 2) & 3) << 2;
        *(uint4*)&xp[nl * 64 + ((k8 * 4) ^ key)] = v;
    }
    __syncthreads();

    int cg = tid & 15;
    int ng = tid >> 4;
    int n0 = ng * 4;
    const int key = (ng & 3) << 2;
    float4 acc0 = {0,0,0,0}, acc1 = {0,0,0,0}, acc2 = {0,0,0,0}, acc3 = {0,0,0,0};

    #pragma unroll 4
    for (int k4 = 0; k4 < 64; k4 += 4) {
        uint4 xq0 = *(uint4*)&xp[(n0 + 0) * 64 + (k4 ^ key)];
        uint4 xq1 = *(uint4*)&xp[(n0 + 1) * 64 + (k4 ^ key)];
        uint4 xq2 = *(uint4*)&xp[(n0 + 2) * 64 + (k4 ^ key)];
        uint4 xq3 = *(uint4*)&xp[(n0 + 3) * 64 + (k4 ^ key)];
        uint4 wq0 = *(uint4*)&Wp[(k4 + 0) * 64 + cg * 4];
        uint4 wq1 = *(uint4*)&Wp[(k4 + 1) * 64 + cg * 4];
        uint4 wq2 = *(uint4*)&Wp[(k4 + 2) * 64 + cg * 4];
        uint4 wq3 = *(uint4*)&Wp[(k4 + 3) * 64 + cg * 4];
        dacc4(acc0, xq0.x, wq0); dacc4(acc0, xq0.y, wq1); dacc4(acc0, xq0.z, wq2); dacc4(acc0, xq0.w, wq3);
        dacc4(acc1, xq1.x, wq0); dacc4(acc1, xq1.y, wq1); dacc4(acc1, xq1.z, wq2); dacc4(acc1, xq1.w, wq3);
        dacc4(acc2, xq2.x, wq0); dacc4(acc2, xq2.y, wq1); dacc4(acc2, xq2.z, wq2); dacc4(acc2, xq2.w, wq3);
        dacc4(acc3, xq3.x, wq0); dacc4(acc3, xq3.y, wq1); dacc4(acc3, xq3.z, wq2); dacc4(acc3, xq3.w, wq3);
    }

    float4 bb = ((const float4*)b1)[cg];
    float4 r[4] = {acc0, acc1, acc2, acc3};
    #pragma unroll
    for (int nl = 0; nl < 4; ++nl) {
        int node = base + n0 + nl;
        float4 v = r[nl];
        v.x = fmaxf(v.x + bb.x, 0.f); v.y = fmaxf(v.y + bb.y, 0.f);
        v.z = fmaxf(v.z + bb.z, 0.f); v.w = fmaxf(v.w + bb.w, 0.f);
        float q = v.x * v.x + v.y * v.y + v.z * v.z + v.w * v.w;
        q = red16(q);
        float rq = rsqrtf(fmaxf(q, 1e-24f));
        if (node < n) {
            X1[(size_t)node * 16 + cg] = make_uint2(pkh(v.x * rq, v.y * rq),
                                                    pkh(v.z * rq, v.w * rq));
            if (cg == 0) nrm1[node] = sqrtf(fmaxf(q, 1e-24f));
        }
    }
}

// ---------------- AGNN propagation ----------------
// one 8-lane group per node (degree-sorted schedule); 2-edge pipelined chains;
// packed fp16 accumulation; no cross-group reduce

template<bool HFOUT>
__global__ __launch_bounds__(256) void k_prop(const uint4* __restrict__ X,
                                              const float* __restrict__ nrm,
                                              const int* __restrict__ row_ptr,
                                              const int* __restrict__ csr_src,
                                              const int* __restrict__ order,
                                              const float* __restrict__ beta_ptr,
                                              uint4* __restrict__ Xout,
                                              float* __restrict__ nrm_out, int n) {
    int gid = (blockIdx.x << 5) + (threadIdx.x >> 3);
    if (gid >= n) return;
    int node = order[gid];
    int gl = threadIdx.x & 7;
    float beta = beta_ptr ? beta_ptr[0] : 1.0f;
    float b2 = beta * 1.4426950408889634f;

    uint4 hdp = X[(unsigned)node * 8u + gl];
    int s0 = row_ptr[node], s1 = row_ptr[node + 1];
    float nd = nrm[node];

    // self-edge: dot(xn,xn)=1 by construction (zero rows: weight exp(0)=1)
    float eself = (nd > 1.5e-12f) ? EXP2(b2) : 1.0f;
    float den = eself;
    half2_t acc[4] = {{0,0},{0,0},{0,0},{0,0}};
    pacc(acc, eself * nd, hdp);

    if (s0 < s1) {
        int i0 = csr_src[s0];
        int i1 = csr_src[s0 + 1];            // padded / in-bounds; gated by v1
        uint4 a0 = X[(unsigned)i0 * 8u + gl];
        uint4 a1 = X[(unsigned)i1 * 8u + gl];
        float n0 = nrm[i0], n1 = nrm[i1];
        bool v1 = s0 + 1 < s1;
        for (int j = s0 + 2; j < s1; j += 2) {
            int i0n = csr_src[j];
            int i1n = csr_src[j + 1];
            uint4 a0n = X[(unsigned)i0n * 8u + gl];
            uint4 a1n = X[(unsigned)i1n * 8u + gl];
            float n0n = nrm[i0n], n1n = nrm[i1n];
            float d0 = red8(dot4(a0, hdp));
            float d1 = red8(dot4(a1, hdp));
            float e0 = EXP2(b2 * d0);
            float e1 = v1 ? EXP2(b2 * d1) : 0.f;
            den += e0 + e1;
            pacc(acc, e0 * n0, a0);
            pacc(acc, e1 * n1, a1);
            a0 = a0n; a1 = a1n; n0 = n0n; n1 = n1n;
            v1 = j + 1 < s1;
        }
        float d0 = red8(dot4(a0, hdp));
        float d1 = red8(dot4(a1, hdp));
        float e0 = EXP2(b2 * d0);
        float e1 = v1 ? EXP2(b2 * d1) : 0.f;
        den += e0 + e1;
        pacc(acc, e0 * n0, a0);
        pacc(acc, e1 * n1, a1);
    }

    float inv = 1.0f / den;
    float o[8];
    #pragma unroll
    for (int c = 0; c < 4; ++c) {
        o[2 * c]     = (float)acc[c][0] * inv;
        o[2 * c + 1] = (float)acc[c][1] * inv;
    }

    if (HFOUT) {
        float q = 0.f;
        #pragma unroll
        for (int c = 0; c < 8; ++c) q += o[c] * o[c];
        q = red8(q);
        float rq = rsqrtf(fmaxf(q, 1e-24f));
        uint4 w;
        w.x = pkh(o[0] * rq, o[1] * rq);
        w.y = pkh(o[2] * rq, o[3] * rq);
        w.z = pkh(o[4] * rq, o[5] * rq);
        w.w = pkh(o[6] * rq, o[7] * rq);
        Xout[(unsigned)node * 8u + gl] = w;
        if (gl == 0) nrm_out[node] = sqrtf(fmaxf(q, 1e-24f));
    } else {
        uint4 w;
        w.x = pkh(o[0], o[1]); w.y = pkh(o[2], o[3]);
        w.z = pkh(o[4], o[5]); w.w = pkh(o[6], o[7]);
        Xout[(unsigned)node * 8u + gl] = w;
    }
}

// ---------------- Linear2 + log_softmax: register-tiled, fp16 input ----------------

__global__ __launch_bounds__(256) void k_out(const uint4* __restrict__ Xh,
                                             const float* __restrict__ W2,
                                             const float* __restrict__ b2,
                                             float* __restrict__ out, int n) {
    __shared__ float hs[ONB * HID];
    __shared__ float W2s[HID * OUTC];
    __shared__ float ls[ONB * LSW];
    int tid = threadIdx.x;
    int base = blockIdx.x * ONB;

    for (int i = tid; i < HID * OUTC / 4; i += 256)
        ((float4*)W2s)[i] = ((const float4*)W2)[i];
    for (int i = tid; i < ONB * 8; i += 256) {
        int nl = i >> 3, k8 = i & 7;
        int gn = base + nl;
        uint4 v = (gn < n) ? Xh[(size_t)gn * 8 + k8] : make_uint4(0, 0, 0, 0);
        float f[8]; unpack8(f, v);
        int key = ((nl >> 2) & 7) << 2;
        *(float4*)&hs[nl * HID + ((k8 * 8) ^ key)]     = make_float4(f[0], f[1], f[2], f[3]);
        *(float4*)&hs[nl * HID + ((k8 * 8 + 4) ^ key)] = make_float4(f[4], f[5], f[6], f[7]);
    }
    __syncthreads();

    if (tid < 240) {
        int ng = tid / 10, cg = tid % 10;
        int n0 = ng * 4;
        const int sw = ((ng & 7) << 2);
        float4 acc0 = {0,0,0,0}, acc1 = {0,0,0,0}, acc2 = {0,0,0,0}, acc3 = {0,0,0,0};
        #pragma unroll 4
        for (int k = 0; k < HID; k += 4) {
            float4 w0 = *(float4*)&W2s[(k + 0) * OUTC + cg * 4];
            float4 w1 = *(float4*)&W2s[(k + 1) * OUTC + cg * 4];
            float4 w2 = *(float4*)&W2s[(k + 2) * OUTC + cg * 4];
            float4 w3 = *(float4*)&W2s[(k + 3) * OUTC + cg * 4];
            float4 x0 = *(float4*)&hs[(n0 + 0) * HID + (k ^ sw)];
            float4 x1 = *(float4*)&hs[(n0 + 1) * HID + (k ^ sw)];
            float4 x2 = *(float4*)&hs[(n0 + 2) * HID + (k ^ sw)];
            float4 x3 = *(float4*)&hs[(n0 + 3) * HID + (k ^ sw)];
            fma4(acc0, x0.x, w0); fma4(acc0, x0.y, w1); fma4(acc0, x0.z, w2); fma4(acc0, x0.w, w3);
            fma4(acc1, x1.x, w0); fma4(acc1, x1.y, w1); fma4(acc1, x1.z, w2); fma4(acc1, x1.w, w3);
            fma4(acc2, x2.x, w0); fma4(acc2, x2.y, w1); fma4(acc2, x2.z, w2); fma4(acc2, x2.w, w3);
            fma4(acc3, x3.x, w0); fma4(acc3, x3.y, w1); fma4(acc3, x3.z, w2); fma4(acc3, x3.w, w3);
        }
        float4 bb = ((const float4*)b2)[cg];
        float4 rr[4] = {acc0, acc1, acc2, acc3};
        #pragma unroll
        for (int i = 0; i < 4; ++i) {
            int lb = (n0 + i) * LSW + cg * 4;
            ls[lb + 0] = rr[i].x + bb.x;
            ls[lb + 1] = rr[i].y + bb.y;
            ls[lb + 2] = rr[i].z + bb.z;
            ls[lb + 3] = rr[i].w + bb.w;
        }
    }
    __syncthreads();

    if (tid < ONB) {
        int node = base + tid;
        if (node < n) {
            float m = -INFINITY;
            #pragma unroll
            for (int c = 0; c < OUTC; ++c) m = fmaxf(m, ls[tid * LSW + c]);
            float z = 0.f;
            #pragma unroll
            for (int c = 0; c < OUTC; ++c) z += __expf(ls[tid * LSW + c] - m);
            float lz = m + __logf(z);
            #pragma unroll
            for (int c = 0; c < OUTC; ++c)
                out[(size_t)node * OUTC + c] = ls[tid * LSW + c] - lz;
        }
    }
}

// ---------------- launch ----------------

extern "C" void kernel_launch(void* const* d_in, const int* in_sizes, int n_in,
                              void* d_out, int out_size, void* d_ws, size_t ws_size,
                              hipStream_t stream) {
    const float* x   = (const float*)d_in[0];
    const int*   ei  = (const int*)d_in[1];
    const float* W1  = (const float*)d_in[2];
    const float* b1  = (const float*)d_in[3];
    const float* W2  = (const float*)d_in[4];
    const float* b2  = (const float*)d_in[5];
    const float* beta2 = (const float*)d_in[6];
    float* out = (float*)d_out;

    const int n = in_sizes[0] / INC;       // 100000
    const int E = in_sizes[1] / 2;         // 1600000
    const int nbuck = (n + (1 << SHIFT) - 1) >> SHIFT;   // 196
    const int cgrid = (E + 4095) / 4096;   // 391
    const int nblk = (n + 255) / 256;      // 391

    // workspace layout
    char* p = (char*)d_ws;
    uint4* X1 = (uint4*)p;             p += (size_t)n * 8 * 16;
    uint4* X2 = (uint4*)p;             p += (size_t)n * 8 * 16;
    uint4* X3 = (uint4*)p;             p += (size_t)n * 8 * 16;
    float* nrm1 = (float*)p;           p += (size_t)n * 4;
    float* nrm2 = (float*)p;           p += (size_t)n * 4;
    int* order = (int*)p;              p += (size_t)n * 4;
    int* bucket_cnt  = (int*)p;        p += MAXB * 4;
    int* dhist       = (int*)p;        p += 256 * 4;
    int* pair_base   = (int*)p;        p += MAXB * 4;
    int* pair_fill   = (int*)p;        p += MAXB * 4;
    int* row_ptr = (int*)p;            p += (size_t)(n + 1) * 4;
    int* csr_src = (int*)p;            p += (size_t)(E + 16) * 4;
    int* blk_cnt = (int*)p;            p += (size_t)cgrid * MAXB * 4;
    unsigned* pairs = (unsigned*)X3;   // alias: pairs dead before prop2 writes X3
    int* blk_dcnt = blk_cnt;           // alias: blk_cnt dead after k_bin

    // CSR build
    (void)hipMemsetAsync(bucket_cnt, 0, MAXB * 4, stream);
    k_hist<<<cgrid, 256, 0, stream>>>(ei, E, bucket_cnt, blk_cnt, nbuck);
    k_bscan<<<1, 256, 0, stream>>>(bucket_cnt, pair_base, pair_fill, row_ptr, csr_src,
                                   n, E, nbuck);
    k_bin<<<cgrid, 256, 0, stream>>>(ei, E, blk_cnt, pair_fill, pairs, nbuck);
    k_build<<<nbuck, 256, 0, stream>>>(pairs, pair_base, bucket_cnt, row_ptr, csr_src, n);

    // degree sort (no contended global atomics)
    k_dhist<<<nblk, 256, 0, stream>>>(row_ptr, blk_dcnt, n);
    k_dcol<<<256, 512, 0, stream>>>(blk_dcnt, dhist, nblk);
    k_dscan<<<1, 256, 0, stream>>>(dhist);
    k_dscatter<<<nblk, 256, 0, stream>>>(row_ptr, dhist, blk_dcnt, order, n);

    // MLP front + props + head
    k_linear1<<<(n + NPB - 1) / NPB, 256, 0, stream>>>(x, W1, b1, (uint2*)X1, nrm1, n);
    int pgrid = (n + 31) / 32;
    k_prop<true><<<pgrid, 256, 0, stream>>>(X1, nrm1, row_ptr, csr_src, order, nullptr,
                                            X2, nrm2, n);
    k_prop<false><<<pgrid, 256, 0, stream>>>(X2, nrm2, row_ptr, csr_src, order, beta2,
                                             X3, nullptr, n);
    k_out<<<(n + ONB - 1) / ONB, 256, 0, stream>>>(X3, W2, b2, out, n);
}

// Round 18
// 193.210 us; speedup vs baseline: 3.6395x; 1.0109x over previous
//
#include <hip/hip_runtime.h>
#include <math.h>

#define INC 128
#define HID 64
#define OUTC 40
#define SHIFT 9
#define MAXB 256
#define NPB 64
#define ONB 96
#define LSW 41
#define SRCM 0x1FFFF
#define PLDS 12288

typedef _Float16 half2_t __attribute__((ext_vector_type(2)));

__device__ inline void fma4(float4& a, float s, const float4& w) {
    a.x += s * w.x; a.y += s * w.y; a.z += s * w.z; a.w += s * w.w;
}
__device__ inline unsigned pkh(float a, float b) {
    unsigned short ua = __builtin_bit_cast(unsigned short, (_Float16)a);
    unsigned short ub = __builtin_bit_cast(unsigned short, (_Float16)b);
    return (unsigned)ua | ((unsigned)ub << 16);
}
__device__ inline float fdot2_(unsigned a, unsigned b, float c) {
#if __has_builtin(__builtin_amdgcn_fdot2)
    return __builtin_amdgcn_fdot2(__builtin_bit_cast(half2_t, a),
                                  __builtin_bit_cast(half2_t, b), c, false);
#else
    half2_t ha = __builtin_bit_cast(half2_t, a);
    half2_t hb = __builtin_bit_cast(half2_t, b);
    return fmaf((float)ha[0], (float)hb[0], fmaf((float)ha[1], (float)hb[1], c));
#endif
}
__device__ inline float dot4(const uint4& a, const uint4& b) {
    float d = fdot2_(a.x, b.x, 0.f);
    d = fdot2_(a.y, b.y, d);
    d = fdot2_(a.z, b.z, d);
    d = fdot2_(a.w, b.w, d);
    return d;
}
__device__ inline void unpack8(float* f, const uint4& a) {
    half2_t p;
    p = __builtin_bit_cast(half2_t, a.x); f[0] = (float)p[0]; f[1] = (float)p[1];
    p = __builtin_bit_cast(half2_t, a.y); f[2] = (float)p[0]; f[3] = (float)p[1];
    p = __builtin_bit_cast(half2_t, a.z); f[4] = (float)p[0]; f[5] = (float)p[1];
    p = __builtin_bit_cast(half2_t, a.w); f[6] = (float)p[0]; f[7] = (float)p[1];
}
__device__ inline void dacc4(float4& a, unsigned xp_, const uint4& w) {
    a.x = fdot2_(xp_, w.x, a.x);
    a.y = fdot2_(xp_, w.y, a.y);
    a.z = fdot2_(xp_, w.z, a.z);
    a.w = fdot2_(xp_, w.w, a.w);
}
// packed fp16 accumulate: acc[0..3] += s * a (8 channels, 4 pk_fma)
__device__ inline void pacc(half2_t* acc, float s, const uint4& a) {
    _Float16 hs = (_Float16)s;
    half2_t s2 = {hs, hs};
    acc[0] += s2 * __builtin_bit_cast(half2_t, a.x);
    acc[1] += s2 * __builtin_bit_cast(half2_t, a.y);
    acc[2] += s2 * __builtin_bit_cast(half2_t, a.z);
    acc[3] += s2 * __builtin_bit_cast(half2_t, a.w);
}
template<int CTRL>
__device__ inline float dppadd(float d) {
    int x = __builtin_amdgcn_update_dpp(0, __builtin_bit_cast(int, d),
                                        CTRL, 0xf, 0xf, true);
    return d + __builtin_bit_cast(float, x);
}
__device__ inline float red8(float d) {
    d = dppadd<0xB1>(d);    // quad_perm xor1
    d = dppadd<0x4E>(d);    // quad_perm xor2
    d = dppadd<0x141>(d);   // row_half_mirror
    return d;
}
__device__ inline float red16(float d) {
    d = dppadd<0xB1>(d);
    d = dppadd<0x4E>(d);
    d = dppadd<0x141>(d);
    d = dppadd<0x140>(d);
    return d;
}
#define EXP2(x) __builtin_amdgcn_exp2f(x)

// ---------------- CSR build: bucketed counting sort (no self loops) ----------------

__global__ __launch_bounds__(256) void k_hist(const int* __restrict__ ei, int E,
                                              int* __restrict__ bucket_cnt,
                                              int* __restrict__ blk_cnt, int nbuck) {
    __shared__ int lh[MAXB];
    int tid = threadIdx.x;
    for (int i = tid; i < nbuck; i += 256) lh[i] = 0;
    __syncthreads();
    int base = blockIdx.x * 4096;
    int end = min(base + 4096, E);
    for (int e = base + tid; e < end; e += 256)
        atomicAdd(&lh[ei[E + e] >> SHIFT], 1);
    __syncthreads();
    for (int i = tid; i < nbuck; i += 256) {
        int v = lh[i];
        blk_cnt[blockIdx.x * MAXB + i] = v;
        if (v) atomicAdd(&bucket_cnt[i], v);
    }
}

__global__ __launch_bounds__(256) void k_bscan(const int* __restrict__ bucket_cnt,
                                               int* __restrict__ pair_base,
                                               int* __restrict__ pair_fill,
                                               int* __restrict__ row_ptr,
                                               int* __restrict__ csr_src,
                                               int n, int E, int nbuck) {
    __shared__ int tmp[MAXB];
    int tid = threadIdx.x;
    int cnt = (tid < nbuck) ? bucket_cnt[tid] : 0;
    tmp[tid] = cnt;
    __syncthreads();
    for (int off = 1; off < 256; off <<= 1) {
        int t = (tid >= off) ? tmp[tid - off] : 0;
        __syncthreads();
        tmp[tid] += t;
        __syncthreads();
    }
    if (tid < nbuck) { int pb = tmp[tid] - cnt; pair_base[tid] = pb; pair_fill[tid] = pb; }
    if (tid == 0) row_ptr[n] = E;
    if (tid < 16) csr_src[E + tid] = 0;   // pad: clamp-free pipelined reads
}

__global__ __launch_bounds__(256) void k_bin(const int* __restrict__ ei, int E,
                                             const int* __restrict__ blk_cnt,
                                             int* __restrict__ pair_fill,
                                             unsigned* __restrict__ pairs, int nbuck) {
    __shared__ int lbase[MAXB];
    int tid = threadIdx.x;
    for (int i = tid; i < nbuck; i += 256) {
        int v = blk_cnt[blockIdx.x * MAXB + i];
        lbase[i] = v ? atomicAdd(&pair_fill[i], v) : 0;
    }
    __syncthreads();
    int base = blockIdx.x * 4096;
    int end = min(base + 4096, E);
    for (int e = base + tid; e < end; e += 256) {
        int s = ei[e], d = ei[E + e];
        int pos = atomicAdd(&lbase[d >> SHIFT], 1);
        pairs[pos] = (unsigned)s | ((unsigned)(d & ((1 << SHIFT) - 1)) << 17);
    }
}

// CSR build + bucket-local degree counting sort (order[] for the prop schedule)
__global__ __launch_bounds__(256) void k_build(const unsigned* __restrict__ pairs,
                                               const int* __restrict__ pair_base,
                                               const int* __restrict__ bucket_cnt,
                                               int* __restrict__ row_ptr,
                                               int* __restrict__ csr_src,
                                               int* __restrict__ order, int n) {
    __shared__ int cnt[1 << SHIFT];
    __shared__ int offs[1 << SHIFT];
    __shared__ int stmp[256];
    __shared__ int dfill[64];
    __shared__ unsigned plds[PLDS];
    int b = blockIdx.x;
    int tid = threadIdx.x;
    int nb0 = b << SHIFT;
    int W = min(n - nb0, 1 << SHIFT);
    int p0 = pair_base[b], pc = bucket_cnt[b];
    bool inl = (pc <= PLDS);

    cnt[tid] = 0; cnt[tid + 256] = 0;
    if (inl) for (int i = tid; i < pc; i += 256) plds[i] = pairs[p0 + i];
    __syncthreads();
    if (inl) {
        for (int i = tid; i < pc; i += 256) atomicAdd(&cnt[plds[i] >> 17], 1);
    } else {
        for (int i = tid; i < pc; i += 256) atomicAdd(&cnt[pairs[p0 + i] >> 17], 1);
    }
    __syncthreads();

    int i0 = 2 * tid, i1 = 2 * tid + 1;
    int s0 = (i0 < W) ? cnt[i0] : 0;
    int s1 = (i1 < W) ? cnt[i1] : 0;
    int ps = s0 + s1;
    stmp[tid] = ps;
    __syncthreads();
    for (int off = 1; off < 256; off <<= 1) {
        int t = (tid >= off) ? stmp[tid - off] : 0;
        __syncthreads();
        stmp[tid] += t;
        __syncthreads();
    }
    int excl = stmp[tid] - ps;
    if (i0 < W) { row_ptr[nb0 + i0] = p0 + excl;      offs[i0] = excl; }
    if (i1 < W) { row_ptr[nb0 + i1] = p0 + excl + s0; offs[i1] = excl + s0; }
    __syncthreads();
    if (inl) {
        for (int i = tid; i < pc; i += 256) {
            unsigned pr = plds[i];
            int pos = atomicAdd(&offs[pr >> 17], 1);
            csr_src[p0 + pos] = (int)(pr & SRCM);
        }
    } else {
        for (int i = tid; i < pc; i += 256) {
            unsigned pr = pairs[p0 + i];
            int pos = atomicAdd(&offs[pr >> 17], 1);
            csr_src[p0 + pos] = (int)(pr & SRCM);
        }
    }

    // ---- bucket-local degree sort into order[nb0 .. nb0+W) ----
    __syncthreads();                       // stmp reuse
    int dg0 = min(s0, 63), dg1 = min(s1, 63);
    if (tid < 64) dfill[tid] = 0;
    __syncthreads();
    if (i0 < W) atomicAdd(&dfill[dg0], 1);
    if (i1 < W) atomicAdd(&dfill[dg1], 1);
    __syncthreads();
    int bv = (tid < 64) ? dfill[tid] : 0;
    stmp[tid] = bv;
    __syncthreads();
    for (int off = 1; off < 64; off <<= 1) {
        int t = (tid >= off && tid < 64) ? stmp[tid - off] : 0;
        __syncthreads();
        if (tid < 64) stmp[tid] += t;
        __syncthreads();
    }
    if (tid < 64) dfill[tid] = stmp[tid] - bv;   // exclusive base
    __syncthreads();
    if (i0 < W) { int pos = atomicAdd(&dfill[dg0], 1); order[nb0 + pos] = nb0 + i0; }
    if (i1 < W) { int pos = atomicAdd(&dfill[dg1], 1); order[nb0 + pos] = nb0 + i1; }
}

// ---------------- Linear1: fp16-pair dot2 GEMM + ReLU + normalize, fp16 out ----------------

__global__ __launch_bounds__(256, 4) void k_linear1(const float* __restrict__ x,
                                                    const float* __restrict__ W1,
                                                    const float* __restrict__ b1,
                                                    uint2* __restrict__ X1,
                                                    float* __restrict__ nrm1, int n) {
    __shared__ unsigned Wp[64 * 64];
    __shared__ unsigned xp[64 * 64];
    int tid = threadIdx.x;
    int base = blockIdx.x * NPB;

    for (int t = tid; t < 1024; t += 256) {
        int kp = t >> 4;
        int c4 = t & 15;
        float4 a = ((const float4*)W1)[(2 * kp) * 16 + c4];
        float4 b = ((const float4*)W1)[(2 * kp + 1) * 16 + c4];
        uint4 w;
        w.x = pkh(a.x, b.x); w.y = pkh(a.y, b.y);
        w.z = pkh(a.z, b.z); w.w = pkh(a.w, b.w);
        *(uint4*)&Wp[kp * 64 + c4 * 4] = w;
    }
    for (int t = tid; t < 1024; t += 256) {
        int nl = t >> 4;
        int k8 = t & 15;
        int gn = base + nl;
        float4 a, b;
        if (gn < n) {
            a = ((const float4*)x)[(size_t)gn * 32 + k8 * 2];
            b = ((const float4*)x)[(size_t)gn * 32 + k8 * 2 + 1];
        } else { a = make_float4(0,0,0,0); b = a; }
        uint4 v;
        v.x = pkh(a.x, a.y); v.y = pkh(a.z, a.w);
        v.z = pkh(b.x, b.y); v.w = pkh(b.z, b.w);
        int key = ((nl >> 2) & 3) << 2;
        *(uint4*)&xp[nl * 64 + ((k8 * 4) ^ key)] = v;
    }
    __syncthreads();

    int cg = tid & 15;
    int ng = tid >> 4;
    int n0 = ng * 4;
    const int key = (ng & 3) << 2;
    float4 acc0 = {0,0,0,0}, acc1 = {0,0,0,0}, acc2 = {0,0,0,0}, acc3 = {0,0,0,0};

    #pragma unroll 4
    for (int k4 = 0; k4 < 64; k4 += 4) {
        uint4 xq0 = *(uint4*)&xp[(n0 + 0) * 64 + (k4 ^ key)];
        uint4 xq1 = *(uint4*)&xp[(n0 + 1) * 64 + (k4 ^ key)];
        uint4 xq2 = *(uint4*)&xp[(n0 + 2) * 64 + (k4 ^ key)];
        uint4 xq3 = *(uint4*)&xp[(n0 + 3) * 64 + (k4 ^ key)];
        uint4 wq0 = *(uint4*)&Wp[(k4 + 0) * 64 + cg * 4];
        uint4 wq1 = *(uint4*)&Wp[(k4 + 1) * 64 + cg * 4];
        uint4 wq2 = *(uint4*)&Wp[(k4 + 2) * 64 + cg * 4];
        uint4 wq3 = *(uint4*)&Wp[(k4 + 3) * 64 + cg * 4];
        dacc4(acc0, xq0.x, wq0); dacc4(acc0, xq0.y, wq1); dacc4(acc0, xq0.z, wq2); dacc4(acc0, xq0.w, wq3);
        dacc4(acc1, xq1.x, wq0); dacc4(acc1, xq1.y, wq1); dacc4(acc1, xq1.z, wq2); dacc4(acc1, xq1.w, wq3);
        dacc4(acc2, xq2.x, wq0); dacc4(acc2, xq2.y, wq1); dacc4(acc2, xq2.z, wq2); dacc4(acc2, xq2.w, wq3);
        dacc4(acc3, xq3.x, wq0); dacc4(acc3, xq3.y, wq1); dacc4(acc3, xq3.z, wq2); dacc4(acc3, xq3.w, wq3);
    }

    float4 bb = ((const float4*)b1)[cg];
    float4 r[4] = {acc0, acc1, acc2, acc3};
    #pragma unroll
    for (int nl = 0; nl < 4; ++nl) {
        int node = base + n0 + nl;
        float4 v = r[nl];
        v.x = fmaxf(v.x + bb.x, 0.f); v.y = fmaxf(v.y + bb.y, 0.f);
        v.z = fmaxf(v.z + bb.z, 0.f); v.w = fmaxf(v.w + bb.w, 0.f);
        float q = v.x * v.x + v.y * v.y + v.z * v.z + v.w * v.w;
        q = red16(q);
        float rq = rsqrtf(fmaxf(q, 1e-24f));
        if (node < n) {
            X1[(size_t)node * 16 + cg] = make_uint2(pkh(v.x * rq, v.y * rq),
                                                    pkh(v.z * rq, v.w * rq));
            if (cg == 0) nrm1[node] = sqrtf(fmaxf(q, 1e-24f));
        }
    }
}

// ---------------- AGNN propagation ----------------
// one 8-lane group per node (bucket-local degree-sorted schedule);
// 2-edge pipelined chains; packed fp16 accumulation; no cross-group reduce

template<bool HFOUT>
__global__ __launch_bounds__(256) void k_prop(const uint4* __restrict__ X,
                                              const float* __restrict__ nrm,
                                              const int* __restrict__ row_ptr,
                                              const int* __restrict__ csr_src,
                                              const int* __restrict__ order,
                                              const float* __restrict__ beta_ptr,
                                              uint4* __restrict__ Xout,
                                              float* __restrict__ nrm_out, int n) {
    int gid = (blockIdx.x << 5) + (threadIdx.x >> 3);
    if (gid >= n) return;
    int node = order[gid];
    int gl = threadIdx.x & 7;
    float beta = beta_ptr ? beta_ptr[0] : 1.0f;
    float b2 = beta * 1.4426950408889634f;

    uint4 hdp = X[(unsigned)node * 8u + gl];
    int s0 = row_ptr[node], s1 = row_ptr[node + 1];
    float nd = nrm[node];

    // self-edge: dot(xn,xn)=1 by construction (zero rows: weight exp(0)=1)
    float eself = (nd > 1.5e-12f) ? EXP2(b2) : 1.0f;
    float den = eself;
    half2_t acc[4] = {{0,0},{0,0},{0,0},{0,0}};
    pacc(acc, eself * nd, hdp);

    if (s0 < s1) {
        int i0 = csr_src[s0];
        int i1 = csr_src[s0 + 1];            // padded / in-bounds; gated by v1
        uint4 a0 = X[(unsigned)i0 * 8u + gl];
        uint4 a1 = X[(unsigned)i1 * 8u + gl];
        float n0 = nrm[i0], n1 = nrm[i1];
        bool v1 = s0 + 1 < s1;
        for (int j = s0 + 2; j < s1; j += 2) {
            int i0n = csr_src[j];
            int i1n = csr_src[j + 1];
            uint4 a0n = X[(unsigned)i0n * 8u + gl];
            uint4 a1n = X[(unsigned)i1n * 8u + gl];
            float n0n = nrm[i0n], n1n = nrm[i1n];
            float d0 = red8(dot4(a0, hdp));
            float d1 = red8(dot4(a1, hdp));
            float e0 = EXP2(b2 * d0);
            float e1 = v1 ? EXP2(b2 * d1) : 0.f;
            den += e0 + e1;
            pacc(acc, e0 * n0, a0);
            pacc(acc, e1 * n1, a1);
            a0 = a0n; a1 = a1n; n0 = n0n; n1 = n1n;
            v1 = j + 1 < s1;
        }
        float d0 = red8(dot4(a0, hdp));
        float d1 = red8(dot4(a1, hdp));
        float e0 = EXP2(b2 * d0);
        float e1 = v1 ? EXP2(b2 * d1) : 0.f;
        den += e0 + e1;
        pacc(acc, e0 * n0, a0);
        pacc(acc, e1 * n1, a1);
    }

    float inv = 1.0f / den;
    float o[8];
    #pragma unroll
    for (int c = 0; c < 4; ++c) {
        o[2 * c]     = (float)acc[c][0] * inv;
        o[2 * c + 1] = (float)acc[c][1] * inv;
    }

    if (HFOUT) {
        float q = 0.f;
        #pragma unroll
        for (int c = 0; c < 8; ++c) q += o[c] * o[c];
        q = red8(q);
        float rq = rsqrtf(fmaxf(q, 1e-24f));
        uint4 w;
        w.x = pkh(o[0] * rq, o[1] * rq);
        w.y = pkh(o[2] * rq, o[3] * rq);
        w.z = pkh(o[4] * rq, o[5] * rq);
        w.w = pkh(o[6] * rq, o[7] * rq);
        Xout[(unsigned)node * 8u + gl] = w;
        if (gl == 0) nrm_out[node] = sqrtf(fmaxf(q, 1e-24f));
    } else {
        uint4 w;
        w.x = pkh(o[0], o[1]); w.y = pkh(o[2], o[3]);
        w.z = pkh(o[4], o[5]); w.w = pkh(o[6], o[7]);
        Xout[(unsigned)node * 8u + gl] = w;
    }
}

// ---------------- Linear2 + log_softmax: register-tiled, fp16 input ----------------

__global__ __launch_bounds__(256) void k_out(const uint4* __restrict__ Xh,
                                             const float* __restrict__ W2,
                                             const float* __restrict__ b2,
                                             float* __restrict__ out, int n) {
    __shared__ float hs[ONB * HID];
    __shared__ float W2s[HID * OUTC];
    __shared__ float ls[ONB * LSW];
    int tid = threadIdx.x;
    int base = blockIdx.x * ONB;

    for (int i = tid; i < HID * OUTC / 4; i += 256)
        ((float4*)W2s)[i] = ((const float4*)W2)[i];
    for (int i = tid; i < ONB * 8; i += 256) {
        int nl = i >> 3, k8 = i & 7;
        int gn = base + nl;
        uint4 v = (gn < n) ? Xh[(size_t)gn * 8 + k8] : make_uint4(0, 0, 0, 0);
        float f[8]; unpack8(f, v);
        int key = ((nl >> 2) & 7) << 2;
        *(float4*)&hs[nl * HID + ((k8 * 8) ^ key)]     = make_float4(f[0], f[1], f[2], f[3]);
        *(float4*)&hs[nl * HID + ((k8 * 8 + 4) ^ key)] = make_float4(f[4], f[5], f[6], f[7]);
    }
    __syncthreads();

    if (tid < 240) {
        int ng = tid / 10, cg = tid % 10;
        int n0 = ng * 4;
        const int sw = ((ng & 7) << 2);
        float4 acc0 = {0,0,0,0}, acc1 = {0,0,0,0}, acc2 = {0,0,0,0}, acc3 = {0,0,0,0};
        #pragma unroll 4
        for (int k = 0; k < HID; k += 4) {
            float4 w0 = *(float4*)&W2s[(k + 0) * OUTC + cg * 4];
            float4 w1 = *(float4*)&W2s[(k + 1) * OUTC + cg * 4];
            float4 w2 = *(float4*)&W2s[(k + 2) * OUTC + cg * 4];
            float4 w3 = *(float4*)&W2s[(k + 3) * OUTC + cg * 4];
            float4 x0 = *(float4*)&hs[(n0 + 0) * HID + (k ^ sw)];
            float4 x1 = *(float4*)&hs[(n0 + 1) * HID + (k ^ sw)];
            float4 x2 = *(float4*)&hs[(n0 + 2) * HID + (k ^ sw)];
            float4 x3 = *(float4*)&hs[(n0 + 3) * HID + (k ^ sw)];
            fma4(acc0, x0.x, w0); fma4(acc0, x0.y, w1); fma4(acc0, x0.z, w2); fma4(acc0, x0.w, w3);
            fma4(acc1, x1.x, w0); fma4(acc1, x1.y, w1); fma4(acc1, x1.z, w2); fma4(acc1, x1.w, w3);
            fma4(acc2, x2.x, w0); fma4(acc2, x2.y, w1); fma4(acc2, x2.z, w2); fma4(acc2, x2.w, w3);
            fma4(acc3, x3.x, w0); fma4(acc3, x3.y, w1); fma4(acc3, x3.z, w2); fma4(acc3, x3.w, w3);
        }
        float4 bb = ((const float4*)b2)[cg];
        float4 rr[4] = {acc0, acc1, acc2, acc3};
        #pragma unroll
        for (int i = 0; i < 4; ++i) {
            int lb = (n0 + i) * LSW + cg * 4;
            ls[lb + 0] = rr[i].x + bb.x;
            ls[lb + 1] = rr[i].y + bb.y;
            ls[lb + 2] = rr[i].z + bb.z;
            ls[lb + 3] = rr[i].w + bb.w;
        }
    }
    __syncthreads();

    if (tid < ONB) {
        int node = base + tid;
        if (node < n) {
            float m = -INFINITY;
            #pragma unroll
            for (int c = 0; c < OUTC; ++c) m = fmaxf(m, ls[tid * LSW + c]);
            float z = 0.f;
            #pragma unroll
            for (int c = 0; c < OUTC; ++c) z += __expf(ls[tid * LSW + c] - m);
            float lz = m + __logf(z);
            #pragma unroll
            for (int c = 0; c < OUTC; ++c)
                out[(size_t)node * OUTC + c] = ls[tid * LSW + c] - lz;
        }
    }
}

// ---------------- launch ----------------

extern "C" void kernel_launch(void* const* d_in, const int* in_sizes, int n_in,
                              void* d_out, int out_size, void* d_ws, size_t ws_size,
                              hipStream_t stream) {
    const float* x   = (const float*)d_in[0];
    const int*   ei  = (const int*)d_in[1];
    const float* W1  = (const float*)d_in[2];
    const float* b1  = (const float*)d_in[3];
    const float* W2  = (const float*)d_in[4];
    const float* b2  = (const float*)d_in[5];
    const float* beta2 = (const float*)d_in[6];
    float* out = (float*)d_out;

    const int n = in_sizes[0] / INC;       // 100000
    const int E = in_sizes[1] / 2;         // 1600000
    const int nbuck = (n + (1 << SHIFT) - 1) >> SHIFT;   // 196
    const int cgrid = (E + 4095) / 4096;   // 391

    // workspace layout
    char* p = (char*)d_ws;
    uint4* X1 = (uint4*)p;             p += (size_t)n * 8 * 16;
    uint4* X2 = (uint4*)p;             p += (size_t)n * 8 * 16;
    uint4* X3 = (uint4*)p;             p += (size_t)n * 8 * 16;
    float* nrm1 = (float*)p;           p += (size_t)n * 4;
    float* nrm2 = (float*)p;           p += (size_t)n * 4;
    int* order = (int*)p;              p += (size_t)n * 4;
    int* bucket_cnt  = (int*)p;        p += MAXB * 4;
    int* pair_base   = (int*)p;        p += MAXB * 4;
    int* pair_fill   = (int*)p;        p += MAXB * 4;
    int* row_ptr = (int*)p;            p += (size_t)(n + 1) * 4;
    int* csr_src = (int*)p;            p += (size_t)(E + 16) * 4;
    int* blk_cnt = (int*)p;            p += (size_t)cgrid * MAXB * 4;
    unsigned* pairs = (unsigned*)X3;   // alias: pairs dead before prop2 writes X3

    // CSR build (order[] comes out of k_build for free)
    (void)hipMemsetAsync(bucket_cnt, 0, MAXB * 4, stream);
    k_hist<<<cgrid, 256, 0, stream>>>(ei, E, bucket_cnt, blk_cnt, nbuck);
    k_bscan<<<1, 256, 0, stream>>>(bucket_cnt, pair_base, pair_fill, row_ptr, csr_src,
                                   n, E, nbuck);
    k_bin<<<cgrid, 256, 0, stream>>>(ei, E, blk_cnt, pair_fill, pairs, nbuck);
    k_build<<<nbuck, 256, 0, stream>>>(pairs, pair_base, bucket_cnt, row_ptr, csr_src,
                                       order, n);

    // MLP front + props + head
    k_linear1<<<(n + NPB - 1) / NPB, 256, 0, stream>>>(x, W1, b1, (uint2*)X1, nrm1, n);
    int pgrid = (n + 31) / 32;
    k_prop<true><<<pgrid, 256, 0, stream>>>(X1, nrm1, row_ptr, csr_src, order, nullptr,
                                            X2, nrm2, n);
    k_prop<false><<<pgrid, 256, 0, stream>>>(X2, nrm2, row_ptr, csr_src, order, beta2,
                                             X3, nullptr, n);
    k_out<<<(n + ONB - 1) / ONB, 256, 0, stream>>>(X3, W2, b2, out, n);
}

// Round 19
// 180.916 us; speedup vs baseline: 3.8868x; 1.0680x over previous
//
#include <hip/hip_runtime.h>
#include <math.h>

#define INC 128
#define HID 64
#define OUTC 40
#define SHIFT 9
#define MAXB 256
#define NPB 64
#define ONB 96
#define LSW 41
#define SRCM 0x1FFFF
#define PLDS 12288

typedef _Float16 half2_t __attribute__((ext_vector_type(2)));

__device__ inline void fma4(float4& a, float s, const float4& w) {
    a.x += s * w.x; a.y += s * w.y; a.z += s * w.z; a.w += s * w.w;
}
__device__ inline unsigned pkh(float a, float b) {
    unsigned short ua = __builtin_bit_cast(unsigned short, (_Float16)a);
    unsigned short ub = __builtin_bit_cast(unsigned short, (_Float16)b);
    return (unsigned)ua | ((unsigned)ub << 16);
}
__device__ inline float fdot2_(unsigned a, unsigned b, float c) {
#if __has_builtin(__builtin_amdgcn_fdot2)
    return __builtin_amdgcn_fdot2(__builtin_bit_cast(half2_t, a),
                                  __builtin_bit_cast(half2_t, b), c, false);
#else
    half2_t ha = __builtin_bit_cast(half2_t, a);
    half2_t hb = __builtin_bit_cast(half2_t, b);
    return fmaf((float)ha[0], (float)hb[0], fmaf((float)ha[1], (float)hb[1], c));
#endif
}
__device__ inline float dot4(const uint4& a, const uint4& b) {
    float d = fdot2_(a.x, b.x, 0.f);
    d = fdot2_(a.y, b.y, d);
    d = fdot2_(a.z, b.z, d);
    d = fdot2_(a.w, b.w, d);
    return d;
}
__device__ inline void unpack8(float* f, const uint4& a) {
    half2_t p;
    p = __builtin_bit_cast(half2_t, a.x); f[0] = (float)p[0]; f[1] = (float)p[1];
    p = __builtin_bit_cast(half2_t, a.y); f[2] = (float)p[0]; f[3] = (float)p[1];
    p = __builtin_bit_cast(half2_t, a.z); f[4] = (float)p[0]; f[5] = (float)p[1];
    p = __builtin_bit_cast(half2_t, a.w); f[6] = (float)p[0]; f[7] = (float)p[1];
}
__device__ inline void dacc4(float4& a, unsigned xp_, const uint4& w) {
    a.x = fdot2_(xp_, w.x, a.x);
    a.y = fdot2_(xp_, w.y, a.y);
    a.z = fdot2_(xp_, w.z, a.z);
    a.w = fdot2_(xp_, w.w, a.w);
}
// packed fp16 accumulate: acc[0..3] += s * a (8 channels, 4 pk_fma)
__device__ inline void pacc(half2_t* acc, float s, const uint4& a) {
    _Float16 hs = (_Float16)s;
    half2_t s2 = {hs, hs};
    acc[0] += s2 * __builtin_bit_cast(half2_t, a.x);
    acc[1] += s2 * __builtin_bit_cast(half2_t, a.y);
    acc[2] += s2 * __builtin_bit_cast(half2_t, a.z);
    acc[3] += s2 * __builtin_bit_cast(half2_t, a.w);
}
template<int CTRL>
__device__ inline float dppadd(float d) {
    int x = __builtin_amdgcn_update_dpp(0, __builtin_bit_cast(int, d),
                                        CTRL, 0xf, 0xf, true);
    return d + __builtin_bit_cast(float, x);
}
__device__ inline float red8(float d) {
    d = dppadd<0xB1>(d);    // quad_perm xor1
    d = dppadd<0x4E>(d);    // quad_perm xor2
    d = dppadd<0x141>(d);   // row_half_mirror
    return d;
}
__device__ inline float red16(float d) {
    d = dppadd<0xB1>(d);
    d = dppadd<0x4E>(d);
    d = dppadd<0x141>(d);
    d = dppadd<0x140>(d);
    return d;
}
#define EXP2(x) __builtin_amdgcn_exp2f(x)

// ---------------- CSR build: bucketed counting sort (no self loops) ----------------

__global__ __launch_bounds__(256) void k_hist(const int* __restrict__ ei, int E,
                                              int* __restrict__ bucket_cnt,
                                              int* __restrict__ blk_cnt, int nbuck) {
    __shared__ int lh[MAXB];
    int tid = threadIdx.x;
    for (int i = tid; i < nbuck; i += 256) lh[i] = 0;
    __syncthreads();
    int base = blockIdx.x * 4096;
    int end = min(base + 4096, E);
    for (int e = base + tid; e < end; e += 256)
        atomicAdd(&lh[ei[E + e] >> SHIFT], 1);
    __syncthreads();
    for (int i = tid; i < nbuck; i += 256) {
        int v = lh[i];
        blk_cnt[blockIdx.x * MAXB + i] = v;
        if (v) atomicAdd(&bucket_cnt[i], v);
    }
}

__global__ __launch_bounds__(256) void k_bscan(const int* __restrict__ bucket_cnt,
                                               int* __restrict__ pair_base,
                                               int* __restrict__ pair_fill,
                                               int* __restrict__ row_ptr,
                                               int* __restrict__ csr_src,
                                               int n, int E, int nbuck) {
    __shared__ int tmp[MAXB];
    int tid = threadIdx.x;
    int cnt = (tid < nbuck) ? bucket_cnt[tid] : 0;
    tmp[tid] = cnt;
    __syncthreads();
    for (int off = 1; off < 256; off <<= 1) {
        int t = (tid >= off) ? tmp[tid - off] : 0;
        __syncthreads();
        tmp[tid] += t;
        __syncthreads();
    }
    if (tid < nbuck) { int pb = tmp[tid] - cnt; pair_base[tid] = pb; pair_fill[tid] = pb; }
    if (tid == 0) row_ptr[n] = E;
    if (tid < 16) csr_src[E + tid] = 0;   // pad: clamp-free pipelined reads
}

__global__ __launch_bounds__(256) void k_bin(const int* __restrict__ ei, int E,
                                             const int* __restrict__ blk_cnt,
                                             int* __restrict__ pair_fill,
                                             unsigned* __restrict__ pairs, int nbuck) {
    __shared__ int lbase[MAXB];
    int tid = threadIdx.x;
    for (int i = tid; i < nbuck; i += 256) {
        int v = blk_cnt[blockIdx.x * MAXB + i];
        lbase[i] = v ? atomicAdd(&pair_fill[i], v) : 0;
    }
    __syncthreads();
    int base = blockIdx.x * 4096;
    int end = min(base + 4096, E);
    for (int e = base + tid; e < end; e += 256) {
        int s = ei[e], d = ei[E + e];
        int pos = atomicAdd(&lbase[d >> SHIFT], 1);
        pairs[pos] = (unsigned)s | ((unsigned)(d & ((1 << SHIFT) - 1)) << 17);
    }
}

__global__ __launch_bounds__(256) void k_build(const unsigned* __restrict__ pairs,
                                               const int* __restrict__ pair_base,
                                               const int* __restrict__ bucket_cnt,
                                               int* __restrict__ row_ptr,
                                               int* __restrict__ csr_src, int n) {
    __shared__ int cnt[1 << SHIFT];
    __shared__ int offs[1 << SHIFT];
    __shared__ int stmp[256];
    __shared__ unsigned plds[PLDS];
    int b = blockIdx.x;
    int tid = threadIdx.x;
    int nb0 = b << SHIFT;
    int W = min(n - nb0, 1 << SHIFT);
    int p0 = pair_base[b], pc = bucket_cnt[b];
    bool inl = (pc <= PLDS);

    cnt[tid] = 0; cnt[tid + 256] = 0;
    if (inl) for (int i = tid; i < pc; i += 256) plds[i] = pairs[p0 + i];
    __syncthreads();
    if (inl) {
        for (int i = tid; i < pc; i += 256) atomicAdd(&cnt[plds[i] >> 17], 1);
    } else {
        for (int i = tid; i < pc; i += 256) atomicAdd(&cnt[pairs[p0 + i] >> 17], 1);
    }
    __syncthreads();

    int i0 = 2 * tid, i1 = 2 * tid + 1;
    int s0 = (i0 < W) ? cnt[i0] : 0;
    int s1 = (i1 < W) ? cnt[i1] : 0;
    int ps = s0 + s1;
    stmp[tid] = ps;
    __syncthreads();
    for (int off = 1; off < 256; off <<= 1) {
        int t = (tid >= off) ? stmp[tid - off] : 0;
        __syncthreads();
        stmp[tid] += t;
        __syncthreads();
    }
    int excl = stmp[tid] - ps;
    if (i0 < W) { row_ptr[nb0 + i0] = p0 + excl;      offs[i0] = excl; }
    if (i1 < W) { row_ptr[nb0 + i1] = p0 + excl + s0; offs[i1] = excl + s0; }
    __syncthreads();
    if (inl) {
        for (int i = tid; i < pc; i += 256) {
            unsigned pr = plds[i];
            int pos = atomicAdd(&offs[pr >> 17], 1);
            csr_src[p0 + pos] = (int)(pr & SRCM);
        }
    } else {
        for (int i = tid; i < pc; i += 256) {
            unsigned pr = pairs[p0 + i];
            int pos = atomicAdd(&offs[pr >> 17], 1);
            csr_src[p0 + pos] = (int)(pr & SRCM);
        }
    }
}

// ---------------- Linear1: fp16-pair dot2 GEMM + ReLU + normalize, fp16 out ----------------

__global__ __launch_bounds__(256, 4) void k_linear1(const float* __restrict__ x,
                                                    const float* __restrict__ W1,
                                                    const float* __restrict__ b1,
                                                    uint2* __restrict__ X1,
                                                    float* __restrict__ nrm1, int n) {
    __shared__ unsigned Wp[64 * 64];
    __shared__ unsigned xp[64 * 64];
    int tid = threadIdx.x;
    int base = blockIdx.x * NPB;

    for (int t = tid; t < 1024; t += 256) {
        int kp = t >> 4;
        int c4 = t & 15;
        float4 a = ((const float4*)W1)[(2 * kp) * 16 + c4];
        float4 b = ((const float4*)W1)[(2 * kp + 1) * 16 + c4];
        uint4 w;
        w.x = pkh(a.x, b.x); w.y = pkh(a.y, b.y);
        w.z = pkh(a.z, b.z); w.w = pkh(a.w, b.w);
        *(uint4*)&Wp[kp * 64 + c4 * 4] = w;
    }
    for (int t = tid; t < 1024; t += 256) {
        int nl = t >> 4;
        int k8 = t & 15;
        int gn = base + nl;
        float4 a, b;
        if (gn < n) {
            a = ((const float4*)x)[(size_t)gn * 32 + k8 * 2];
            b = ((const float4*)x)[(size_t)gn * 32 + k8 * 2 + 1];
        } else { a = make_float4(0,0,0,0); b = a; }
        uint4 v;
        v.x = pkh(a.x, a.y); v.y = pkh(a.z, a.w);
        v.z = pkh(b.x, b.y); v.w = pkh(b.z, b.w);
        int key = ((nl >> 2) & 3) << 2;
        *(uint4*)&xp[nl * 64 + ((k8 * 4) ^ key)] = v;
    }
    __syncthreads();

    int cg = tid & 15;
    int ng = tid >> 4;
    int n0 = ng * 4;
    const int key = (ng & 3) << 2;
    float4 acc0 = {0,0,0,0}, acc1 = {0,0,0,0}, acc2 = {0,0,0,0}, acc3 = {0,0,0,0};

    #pragma unroll 4
    for (int k4 = 0; k4 < 64; k4 += 4) {
        uint4 xq0 = *(uint4*)&xp[(n0 + 0) * 64 + (k4 ^ key)];
        uint4 xq1 = *(uint4*)&xp[(n0 + 1) * 64 + (k4 ^ key)];
        uint4 xq2 = *(uint4*)&xp[(n0 + 2) * 64 + (k4 ^ key)];
        uint4 xq3 = *(uint4*)&xp[(n0 + 3) * 64 + (k4 ^ key)];
        uint4 wq0 = *(uint4*)&Wp[(k4 + 0) * 64 + cg * 4];
        uint4 wq1 = *(uint4*)&Wp[(k4 + 1) * 64 + cg * 4];
        uint4 wq2 = *(uint4*)&Wp[(k4 + 2) * 64 + cg * 4];
        uint4 wq3 = *(uint4*)&Wp[(k4 + 3) * 64 + cg * 4];
        dacc4(acc0, xq0.x, wq0); dacc4(acc0, xq0.y, wq1); dacc4(acc0, xq0.z, wq2); dacc4(acc0, xq0.w, wq3);
        dacc4(acc1, xq1.x, wq0); dacc4(acc1, xq1.y, wq1); dacc4(acc1, xq1.z, wq2); dacc4(acc1, xq1.w, wq3);
        dacc4(acc2, xq2.x, wq0); dacc4(acc2, xq2.y, wq1); dacc4(acc2, xq2.z, wq2); dacc4(acc2, xq2.w, wq3);
        dacc4(acc3, xq3.x, wq0); dacc4(acc3, xq3.y, wq1); dacc4(acc3, xq3.z, wq2); dacc4(acc3, xq3.w, wq3);
    }

    float4 bb = ((const float4*)b1)[cg];
    float4 r[4] = {acc0, acc1, acc2, acc3};
    #pragma unroll
    for (int nl = 0; nl < 4; ++nl) {
        int node = base + n0 + nl;
        float4 v = r[nl];
        v.x = fmaxf(v.x + bb.x, 0.f); v.y = fmaxf(v.y + bb.y, 0.f);
        v.z = fmaxf(v.z + bb.z, 0.f); v.w = fmaxf(v.w + bb.w, 0.f);
        float q = v.x * v.x + v.y * v.y + v.z * v.z + v.w * v.w;
        q = red16(q);
        float rq = rsqrtf(fmaxf(q, 1e-24f));
        if (node < n) {
            X1[(size_t)node * 16 + cg] = make_uint2(pkh(v.x * rq, v.y * rq),
                                                    pkh(v.z * rq, v.w * rq));
            if (cg == 0) nrm1[node] = sqrtf(fmaxf(q, 1e-24f));
        }
    }
}

// ---------------- AGNN propagation ----------------
// 2-deep pipelined 16-edge loop; packed fp16 accumulation; packed epilogue reduce

template<bool HFOUT>
__global__ __launch_bounds__(256) void k_prop(const uint4* __restrict__ X,
                                              const float* __restrict__ nrm,
                                              const int* __restrict__ row_ptr,
                                              const int* __restrict__ csr_src,
                                              const float* __restrict__ beta_ptr,
                                              uint4* __restrict__ Xout,
                                              float* __restrict__ nrm_out, int n) {
    int node = blockIdx.x * 4 + (threadIdx.x >> 6);
    if (node >= n) return;
    int lane = threadIdx.x & 63;
    int g = lane >> 3, gl = lane & 7;
    float beta = beta_ptr ? beta_ptr[0] : 1.0f;
    float b2 = beta * 1.4426950408889634f;

    uint4 hdp = X[(unsigned)node * 8u + gl];
    int s0 = row_ptr[node], s1 = row_ptr[node + 1];
    float nd = nrm[node];

    // self-edge: dot(xn,xn)=1 by construction (zero rows: weight exp(0)=1)
    float eself = (nd > 1.5e-12f) ? EXP2(b2) : 1.0f;
    float den0 = (g == 0) ? eself : 0.f;
    float den1 = 0.f;
    half2_t acc[4] = {{0,0},{0,0},{0,0},{0,0}};
    pacc(acc, (g == 0) ? eself * nd : 0.f, hdp);

    if (s0 < s1) {
        int i0 = csr_src[s0 + g];          // csr_src padded by 16 -> no clamp
        int i1 = csr_src[s0 + 8 + g];
        uint4 a0 = X[(unsigned)i0 * 8u + gl];
        uint4 a1 = X[(unsigned)i1 * 8u + gl];
        float n0 = nrm[i0], n1 = nrm[i1];
        bool v0 = s0 + g < s1, v1 = s0 + 8 + g < s1;
        for (int j = s0 + 16; j < s1; j += 16) {
            int i0n = csr_src[j + g];
            int i1n = csr_src[j + 8 + g];
            uint4 a0n = X[(unsigned)i0n * 8u + gl];
            uint4 a1n = X[(unsigned)i1n * 8u + gl];
            float n0n = nrm[i0n], n1n = nrm[i1n];
            float d0 = red8(dot4(a0, hdp));
            float d1 = red8(dot4(a1, hdp));
            float e0 = v0 ? EXP2(b2 * d0) : 0.f;
            float e1 = v1 ? EXP2(b2 * d1) : 0.f;
            den0 += e0; den1 += e1;
            pacc(acc, e0 * n0, a0);
            pacc(acc, e1 * n1, a1);
            a0 = a0n; a1 = a1n; n0 = n0n; n1 = n1n;
            v0 = j + g < s1; v1 = j + 8 + g < s1;
        }
        float d0 = red8(dot4(a0, hdp));
        float d1 = red8(dot4(a1, hdp));
        float e0 = v0 ? EXP2(b2 * d0) : 0.f;
        float e1 = v1 ? EXP2(b2 * d1) : 0.f;
        den0 += e0; den1 += e1;
        pacc(acc, e0 * n0, a0);
        pacc(acc, e1 * n1, a1);
    }

    // cross-group reduce: 4 packed regs + den over 3 rounds
    float den = den0 + den1;
    #pragma unroll
    for (int r = 8; r <= 32; r <<= 1) {
        #pragma unroll
        for (int c = 0; c < 4; ++c) {
            unsigned u = __shfl_xor(__builtin_bit_cast(unsigned, acc[c]), r, 64);
            acc[c] += __builtin_bit_cast(half2_t, u);
        }
        den += __shfl_xor(den, r, 64);
    }
    float inv = 1.0f / den;
    float o[8];
    #pragma unroll
    for (int c = 0; c < 4; ++c) {
        o[2 * c]     = (float)acc[c][0] * inv;
        o[2 * c + 1] = (float)acc[c][1] * inv;
    }

    if (HFOUT) {
        float q = 0.f;
        #pragma unroll
        for (int c = 0; c < 8; ++c) q += o[c] * o[c];
        q = red8(q);
        float rq = rsqrtf(fmaxf(q, 1e-24f));
        if (g == 0) {
            uint4 w;
            w.x = pkh(o[0] * rq, o[1] * rq);
            w.y = pkh(o[2] * rq, o[3] * rq);
            w.z = pkh(o[4] * rq, o[5] * rq);
            w.w = pkh(o[6] * rq, o[7] * rq);
            Xout[(unsigned)node * 8u + gl] = w;
            if (gl == 0) nrm_out[node] = sqrtf(fmaxf(q, 1e-24f));
        }
    } else {
        if (g == 0) {
            uint4 w;
            w.x = pkh(o[0], o[1]); w.y = pkh(o[2], o[3]);
            w.z = pkh(o[4], o[5]); w.w = pkh(o[6], o[7]);
            Xout[(unsigned)node * 8u + gl] = w;
        }
    }
}

// ---------------- Linear2 + log_softmax: register-tiled, fp16 input ----------------

__global__ __launch_bounds__(256) void k_out(const uint4* __restrict__ Xh,
                                             const float* __restrict__ W2,
                                             const float* __restrict__ b2,
                                             float* __restrict__ out, int n) {
    __shared__ float hs[ONB * HID];
    __shared__ float W2s[HID * OUTC];
    __shared__ float ls[ONB * LSW];
    int tid = threadIdx.x;
    int base = blockIdx.x * ONB;

    for (int i = tid; i < HID * OUTC / 4; i += 256)
        ((float4*)W2s)[i] = ((const float4*)W2)[i];
    for (int i = tid; i < ONB * 8; i += 256) {
        int nl = i >> 3, k8 = i & 7;
        int gn = base + nl;
        uint4 v = (gn < n) ? Xh[(size_t)gn * 8 + k8] : make_uint4(0, 0, 0, 0);
        float f[8]; unpack8(f, v);
        int key = ((nl >> 2) & 7) << 2;
        *(float4*)&hs[nl * HID + ((k8 * 8) ^ key)]     = make_float4(f[0], f[1], f[2], f[3]);
        *(float4*)&hs[nl * HID + ((k8 * 8 + 4) ^ key)] = make_float4(f[4], f[5], f[6], f[7]);
    }
    __syncthreads();

    if (tid < 240) {
        int ng = tid / 10, cg = tid % 10;
        int n0 = ng * 4;
        const int sw = ((ng & 7) << 2);
        float4 acc0 = {0,0,0,0}, acc1 = {0,0,0,0}, acc2 = {0,0,0,0}, acc3 = {0,0,0,0};
        #pragma unroll 4
        for (int k = 0; k < HID; k += 4) {
            float4 w0 = *(float4*)&W2s[(k + 0) * OUTC + cg * 4];
            float4 w1 = *(float4*)&W2s[(k + 1) * OUTC + cg * 4];
            float4 w2 = *(float4*)&W2s[(k + 2) * OUTC + cg * 4];
            float4 w3 = *(float4*)&W2s[(k + 3) * OUTC + cg * 4];
            float4 x0 = *(float4*)&hs[(n0 + 0) * HID + (k ^ sw)];
            float4 x1 = *(float4*)&hs[(n0 + 1) * HID + (k ^ sw)];
            float4 x2 = *(float4*)&hs[(n0 + 2) * HID + (k ^ sw)];
            float4 x3 = *(float4*)&hs[(n0 + 3) * HID + (k ^ sw)];
            fma4(acc0, x0.x, w0); fma4(acc0, x0.y, w1); fma4(acc0, x0.z, w2); fma4(acc0, x0.w, w3);
            fma4(acc1, x1.x, w0); fma4(acc1, x1.y, w1); fma4(acc1, x1.z, w2); fma4(acc1, x1.w, w3);
            fma4(acc2, x2.x, w0); fma4(acc2, x2.y, w1); fma4(acc2, x2.z, w2); fma4(acc2, x2.w, w3);
            fma4(acc3, x3.x, w0); fma4(acc3, x3.y, w1); fma4(acc3, x3.z, w2); fma4(acc3, x3.w, w3);
        }
        float4 bb = ((const float4*)b2)[cg];
        float4 rr[4] = {acc0, acc1, acc2, acc3};
        #pragma unroll
        for (int i = 0; i < 4; ++i) {
            int lb = (n0 + i) * LSW + cg * 4;
            ls[lb + 0] = rr[i].x + bb.x;
            ls[lb + 1] = rr[i].y + bb.y;
            ls[lb + 2] = rr[i].z + bb.z;
            ls[lb + 3] = rr[i].w + bb.w;
        }
    }
    __syncthreads();

    if (tid < ONB) {
        int node = base + tid;
        if (node < n) {
            float m = -INFINITY;
            #pragma unroll
            for (int c = 0; c < OUTC; ++c) m = fmaxf(m, ls[tid * LSW + c]);
            float z = 0.f;
            #pragma unroll
            for (int c = 0; c < OUTC; ++c) z += __expf(ls[tid * LSW + c] - m);
            float lz = m + __logf(z);
            #pragma unroll
            for (int c = 0; c < OUTC; ++c)
                out[(size_t)node * OUTC + c] = ls[tid * LSW + c] - lz;
        }
    }
}

// ---------------- launch ----------------

extern "C" void kernel_launch(void* const* d_in, const int* in_sizes, int n_in,
                              void* d_out, int out_size, void* d_ws, size_t ws_size,
                              hipStream_t stream) {
    const float* x   = (const float*)d_in[0];
    const int*   ei  = (const int*)d_in[1];
    const float* W1  = (const float*)d_in[2];
    const float* b1  = (const float*)d_in[3];
    const float* W2  = (const float*)d_in[4];
    const float* b2  = (const float*)d_in[5];
    const float* beta2 = (const float*)d_in[6];
    float* out = (float*)d_out;

    const int n = in_sizes[0] / INC;       // 100000
    const int E = in_sizes[1] / 2;         // 1600000
    const int nbuck = (n + (1 << SHIFT) - 1) >> SHIFT;   // 196
    const int cgrid = (E + 4095) / 4096;   // 391

    // workspace layout
    char* p = (char*)d_ws;
    uint4* X1 = (uint4*)p;             p += (size_t)n * 8 * 16;
    uint4* X2 = (uint4*)p;             p += (size_t)n * 8 * 16;
    uint4* X3 = (uint4*)p;             p += (size_t)n * 8 * 16;
    float* nrm1 = (float*)p;           p += (size_t)n * 4;
    float* nrm2 = (float*)p;           p += (size_t)n * 4;
    int* bucket_cnt  = (int*)p;        p += MAXB * 4;
    int* pair_base   = (int*)p;        p += MAXB * 4;
    int* pair_fill   = (int*)p;        p += MAXB * 4;
    int* row_ptr = (int*)p;            p += (size_t)(n + 1) * 4;
    int* csr_src = (int*)p;            p += (size_t)(E + 16) * 4;
    int* blk_cnt = (int*)p;            p += (size_t)cgrid * MAXB * 4;
    unsigned* pairs = (unsigned*)X3;   // alias: pairs dead before prop2 writes X3

    // CSR build
    (void)hipMemsetAsync(bucket_cnt, 0, MAXB * 4, stream);
    k_hist<<<cgrid, 256, 0, stream>>>(ei, E, bucket_cnt, blk_cnt, nbuck);
    k_bscan<<<1, 256, 0, stream>>>(bucket_cnt, pair_base, pair_fill, row_ptr, csr_src,
                                   n, E, nbuck);
    k_bin<<<cgrid, 256, 0, stream>>>(ei, E, blk_cnt, pair_fill, pairs, nbuck);
    k_build<<<nbuck, 256, 0, stream>>>(pairs, pair_base, bucket_cnt, row_ptr, csr_src, n);

    // MLP front + props + head
    k_linear1<<<(n + NPB - 1) / NPB, 256, 0, stream>>>(x, W1, b1, (uint2*)X1, nrm1, n);
    int pgrid = (n + 3) / 4;
    k_prop<true><<<pgrid, 256, 0, stream>>>(X1, nrm1, row_ptr, csr_src, nullptr,
                                            X2, nrm2, n);
    k_prop<false><<<pgrid, 256, 0, stream>>>(X2, nrm2, row_ptr, csr_src, beta2,
                                             X3, nullptr, n);
    k_out<<<(n + ONB - 1) / ONB, 256, 0, stream>>>(X3, W2, b2, out, n);
}